// Round 20
// baseline (268.340 us; speedup 1.0000x reference)
//
#include <hip/hip_runtime.h>

#define BN 16384
#define DD 16
#define KNN 25
#define QB 16
#define CAPH 128
#define NSQ 4

typedef unsigned long long u64;
typedef __attribute__((ext_vector_type(8))) short bf16x8;
typedef __attribute__((ext_vector_type(4))) float f32x4;

__device__ __forceinline__ u64 wave_min_u64(u64 v) {
#pragma unroll
    for (int off = 32; off >= 1; off >>= 1) {
        unsigned lo = (unsigned)v, hi = (unsigned)(v >> 32);
        unsigned olo = __shfl_xor(lo, off, 64);
        unsigned ohi = __shfl_xor(hi, off, 64);
        u64 o = (((u64)ohi) << 32) | olo;
        if (o < v) v = o;
    }
    return v;
}

__device__ __forceinline__ unsigned short f2bf(float f) {
    unsigned u = __float_as_uint(f);
    unsigned r = (u + 0x7FFFu + ((u >> 16) & 1u)) >> 16;   // RNE
    return (unsigned short)r;
}

// ---------------- prep: norms + split-precision bf16 [hi(16)|lo(16)] ----------------
__global__ void prep_kernel(const float* __restrict__ raw, uint4* __restrict__ rawhl,
                            float* __restrict__ nrm) {
    int j = blockIdx.x * 256 + threadIdx.x;
    if (j >= BN) return;
    const float4* rv = (const float4*)raw + j * 4;
    float4 a = rv[0], b = rv[1], c = rv[2], d = rv[3];
    float x[16] = {a.x,a.y,a.z,a.w,b.x,b.y,b.z,b.w,c.x,c.y,c.z,c.w,d.x,d.y,d.z,d.w};
    float s = 0.f;
#pragma unroll
    for (int i = 0; i < 16; ++i) s = fmaf(x[i], x[i], s);
    nrm[j] = s;
    unsigned hp[8], lp[8];
#pragma unroll
    for (int i = 0; i < 8; ++i) {
        unsigned short h0 = f2bf(x[2*i]), h1 = f2bf(x[2*i+1]);
        float f0 = __uint_as_float(((unsigned)h0) << 16);
        float f1 = __uint_as_float(((unsigned)h1) << 16);
        unsigned short l0 = f2bf(x[2*i] - f0), l1 = f2bf(x[2*i+1] - f1);
        hp[i] = (unsigned)h0 | ((unsigned)h1 << 16);
        lp[i] = (unsigned)l0 | ((unsigned)l1 << 16);
    }
    uint4* dst = rawhl + j * 4;
    dst[0] = make_uint4(hp[0], hp[1], hp[2], hp[3]);
    dst[1] = make_uint4(hp[4], hp[5], hp[6], hp[7]);
    dst[2] = make_uint4(lp[0], lp[1], lp[2], lp[3]);
    dst[3] = make_uint4(lp[4], lp[5], lp[6], lp[7]);
}

// ---------------- recon partials ----------------
__global__ void recon_kernel(const float* __restrict__ o, const float* __restrict__ t,
                             float* __restrict__ part) {
    __shared__ float red[256];
    int tid = threadIdx.x;
    int idx = blockIdx.x * 256 + tid;
    float s = 0.f;
    for (int i = idx; i < BN * DD; i += 256 * 256) {
        float d = o[i] - t[i];
        s = fmaf(d, d, s);
    }
    red[tid] = s;
    __syncthreads();
    for (int off = 128; off > 0; off >>= 1) {
        if (tid < off) red[tid] += red[tid + off];
        __syncthreads();
    }
    if (tid == 0) part[blockIdx.x] = red[0];
}

// ------- bounds: one global bound per query from first-4096 sample -------
__global__ __launch_bounds__(256, 8) void bounds_kernel(const uint4* __restrict__ rawhl,
                                                        const float* __restrict__ nrm,
                                                        float* __restrict__ bndp) {
    const int tid  = threadIdx.x;
    const int lane = tid & 63;
    const int w    = tid >> 6;
    const int l15  = lane & 15;
    const int g    = lane >> 4;
    const int row0 = blockIdx.x * QB;

    __shared__ float minbuf[QB][64];   // 4 KB

    const bf16x8* rb = (const bf16x8*)rawhl;
    bf16x8 A1 = rb[(row0 + l15) * 4 + (g & 1)];
    bf16x8 A2 = rb[(row0 + l15) * 4 + 2 + (g & 1)];
    float4 vqn = *(const float4*)(nrm + row0 + g * 4);

    const float INFf = __builtin_inff();
    float mn0 = INFf, mn1 = INFf, mn2 = INFf, mn3 = INFf;
    for (int t = w; t < 256; t += 4) {
        int pt = t * 16 + l15;
        bf16x8 Bf = rb[pt * 4 + g];
        float pn = nrm[pt];
        f32x4 c = {0.f, 0.f, 0.f, 0.f};
        c = __builtin_amdgcn_mfma_f32_16x16x32_bf16(A1, Bf, c, 0, 0, 0);
        c = __builtin_amdgcn_mfma_f32_16x16x32_bf16(A2, Bf, c, 0, 0, 0);
        mn0 = fminf(mn0, fmaxf(fmaf(-2.f, c[0], vqn.x + pn), 0.f));
        mn1 = fminf(mn1, fmaxf(fmaf(-2.f, c[1], vqn.y + pn), 0.f));
        mn2 = fminf(mn2, fmaxf(fmaf(-2.f, c[2], vqn.z + pn), 0.f));
        mn3 = fminf(mn3, fmaxf(fmaf(-2.f, c[3], vqn.w + pn), 0.f));
    }
    minbuf[g * 4 + 0][w * 16 + l15] = mn0;
    minbuf[g * 4 + 1][w * 16 + l15] = mn1;
    minbuf[g * 4 + 2][w * 16 + l15] = mn2;
    minbuf[g * 4 + 3][w * 16 + l15] = mn3;
    __syncthreads();

    // 26 value-extractions: each retires >=1 distinct point's min => bound
    // >= true 26th-smallest over the sample >= global 26th-smallest.
    for (int rr = 0; rr < 4; ++rr) {
        int row = 4 * w + rr;
        float v = minbuf[row][lane];
        float bk = INFf;
        for (int it = 0; it < KNN + 1; ++it) {
            float m = v;
#pragma unroll
            for (int off = 32; off >= 1; off >>= 1)
                m = fminf(m, __shfl_xor(m, off, 64));
            bk = m;
            if (v == m) v = INFf;
        }
        // pre-shifted compare constant: (pn - 2c) <= bk - qn (+ rounding margin)
        if (lane == 0) bndp[row0 + row] = bk - nrm[row0 + row] + 1e-3f;
    }
}

// ------- knnb: 16 rows x half-point-range; pure collect scan, LDS lists -------
__global__ __launch_bounds__(256, 8) void knnb_kernel(const uint4* __restrict__ rawhl,
                                                      const float* __restrict__ nrm,
                                                      const float* __restrict__ bndp,
                                                      unsigned* __restrict__ gcnt2,
                                                      u64* __restrict__ glist) {
    const int tid  = threadIdx.x;
    const int lane = tid & 63;
    const int w    = tid >> 6;
    const int l15  = lane & 15;
    const int g    = lane >> 4;
    const int qg   = blockIdx.x >> 1;
    const int h    = blockIdx.x & 1;
    const int row0 = qg * QB;
    const int pbase = h * (BN / 2);

    __shared__ __align__(16) u64 lists[QB][CAPH];   // 16 KB
    __shared__ int lcnt[QB];

    if (tid < QB) lcnt[tid] = 0;
    __syncthreads();

    const bf16x8* rb = (const bf16x8*)rawhl;
    bf16x8 A1 = rb[(row0 + l15) * 4 + (g & 1)];
    bf16x8 A2 = rb[(row0 + l15) * 4 + 2 + (g & 1)];
    float4 vqn = *(const float4*)(nrm + row0 + g * 4);
    float4 vbp = *(const float4*)(bndp + row0 + g * 4);

    // ---- single pass over this half: 2 VALU/dot test, rare collect ----
    for (int t = w; t < 512; t += 4) {
        int pt = pbase + t * 16 + l15;
        bf16x8 Bf = rb[pt * 4 + g];
        float pn = nrm[pt];
        f32x4 c = {0.f, 0.f, 0.f, 0.f};
        c = __builtin_amdgcn_mfma_f32_16x16x32_bf16(A1, Bf, c, 0, 0, 0);
        c = __builtin_amdgcn_mfma_f32_16x16x32_bf16(A2, Bf, c, 0, 0, 0);
#define COLL(r, QN, BB) { \
        float s = fmaf(-2.f, c[r], pn); \
        if (s <= BB) { \
            float d2 = fmaxf(s + QN, 0.f); \
            int q = g * 4 + r; \
            int pos = atomicAdd(&lcnt[q], 1); \
            if (pos < CAPH) \
                lists[q][pos] = (((u64)__float_as_uint(d2)) << 32) | (unsigned)pt; } }
        COLL(0, vqn.x, vbp.x) COLL(1, vqn.y, vbp.y)
        COLL(2, vqn.z, vbp.z) COLL(3, vqn.w, vbp.w)
#undef COLL
    }
    __syncthreads();

    // ---- flush: coalesced bulk writes, one count store per query-half ----
    for (int rr = 0; rr < 4; ++rr) {
        int qi = 4 * w + rr;
        int cnt = lcnt[qi]; if (cnt > CAPH) cnt = CAPH;
        u64* dst = glist + ((u64)(row0 + qi) * 2 + h) * CAPH;
        for (int e = lane; e < cnt; e += 64) dst[e] = lists[qi][e];
        if (lane == 0) gcnt2[(row0 + qi) * 2 + h] = (unsigned)cnt;
    }
}

// ------------- sel_eigen: 1 row per wave; top-25 select, MFMA eigen solve -------------
// LDS overlay: pts (640 f) is dead once Fh/Fl fragments are built, so Arow/Acol
// (320+320 f) reuse its region -> 720 f/wave -> 11.5 KB/block -> 8 blocks/CU.
__global__ __launch_bounds__(256, 8) void sel_eigen_kernel(const float* __restrict__ latent,
                                                           const float* __restrict__ raw,
                                                           const unsigned* __restrict__ gcnt2,
                                                           const u64* __restrict__ glist,
                                                           float* __restrict__ tsa) {
    const int lane = threadIdx.x & 63;
    const int w    = threadIdx.x >> 6;
    const int l15  = lane & 15;
    const int g    = lane >> 4;
    const int qi   = blockIdx.x * 4 + w;

    __shared__ __align__(16) float smem[4 * 720];   // 11.25 KB, wave-private slices
    float* ews  = smem + w * 720;
    float* pts  = ews;            // [0,640): 32 rows x stride 20 (overlaid later)
    float* Arow = ews;            // [0,320): A[r][c] at r*20+c   (overlay on pts)
    float* Acol = ews + 320;      // [320,640): A[r][c] at c*20+r (overlay on pts)
    float* vbuf = ews + 640;      // 16
    float* ubuf = ews + 656;      // 32
    int*   nbrw = (int*)(ews + 688); // 25

    // ---- selection: merge 2 half-lists, register 26 extract-mins (iter 0 = self) ----
    {
        int c0 = (int)gcnt2[qi * 2 + 0]; if (c0 > CAPH) c0 = CAPH;
        int c1 = (int)gcnt2[qi * 2 + 1]; if (c1 > CAPH) c1 = CAPH;
        const u64* L = glist + (u64)qi * 2 * CAPH;
        u64 k0, k1, k2, k3;
#define GET(dst, i) { int ii = (i); \
        if (ii < c0) dst = L[ii]; \
        else { int jj = ii - c0; dst = (jj < c1) ? L[CAPH + jj] : ~0ull; } }
        GET(k0, lane) GET(k1, lane + 64) GET(k2, lane + 128) GET(k3, lane + 192)
#undef GET
        for (int it = 0; it < KNN + 1; ++it) {
            u64 best = k0;
            if (k1 < best) best = k1;
            if (k2 < best) best = k2;
            if (k3 < best) best = k3;
            best = wave_min_u64(best);
            if (k0 == best) k0 = ~0ull;
            if (k1 == best) k1 = ~0ull;
            if (k2 == best) k2 = ~0ull;
            if (k3 == best) k3 = ~0ull;
            if (lane == 0 && it > 0) nbrw[it - 1] = (int)(best & 0xffffffffu);
        }
    }

    const int q4 = g << 2;
    const int jc = l15;
    const int c8 = 8 * (g & 1);
    const float i25 = 1.0f / 25.0f;

    // ones A-fragment for column-sum MFMA: A[0][k]=1, rows 1..15 = 0
    bf16x8 Fones;
#pragma unroll
    for (int i = 0; i < 8; ++i) Fones[i] = (l15 == 0) ? (short)0x3F80 : (short)0;

    for (int m = 0; m < 2; ++m) {
        const float4* src4 = (const float4*)((m == 0) ? latent : raw);
        // write pts rows 0..24 (Arow/Acol of previous iteration are dead here)
        if (lane < KNN) {
            int nb = nbrw[lane];
            float4 r0 = src4[nb * 4 + 0], r1 = src4[nb * 4 + 1];
            float4 r2 = src4[nb * 4 + 2], r3 = src4[nb * 4 + 3];
            float4* dst = (float4*)(pts + lane * 20);
            dst[0] = r0; dst[1] = r1; dst[2] = r2; dst[3] = r3;
        }
        // zero pad rows 25..31 (re-done each m: overlay clobbers it)
        if (lane >= 25 && lane < 32) {
            float4 z = make_float4(0.f, 0.f, 0.f, 0.f);
            float4* dst = (float4*)(pts + lane * 20);
            dst[0] = z; dst[1] = z; dst[2] = z; dst[3] = z;
        }

        // ---- P fragments: F = P[8g+i][l15] (serves as A=P^T and B=P) ----
        bf16x8 Fh, Fl;
#pragma unroll
        for (int i = 0; i < 8; ++i) {
            float pv = pts[(8 * g + i) * 20 + l15];
            unsigned short hh = f2bf(pv);
            float hf = __uint_as_float(((unsigned)hh) << 16);
            unsigned short ll = f2bf(pv - hf);
            Fh[i] = (short)hh;
            Fl[i] = (short)ll;
        }
        // pts is DEAD from here on; Arow/Acol may overwrite its region.

        // ---- gram G = P^T P (4 MFMAs, full hi/lo cross terms) ----
        f32x4 gacc = {0.f, 0.f, 0.f, 0.f};
        gacc = __builtin_amdgcn_mfma_f32_16x16x32_bf16(Fh, Fh, gacc, 0, 0, 0);
        gacc = __builtin_amdgcn_mfma_f32_16x16x32_bf16(Fh, Fl, gacc, 0, 0, 0);
        gacc = __builtin_amdgcn_mfma_f32_16x16x32_bf16(Fl, Fh, gacc, 0, 0, 0);
        gacc = __builtin_amdgcn_mfma_f32_16x16x32_bf16(Fl, Fl, gacc, 0, 0, 0);

        // ---- column sums s = 1^T P via ones-row MFMA ----
        f32x4 sacc = {0.f, 0.f, 0.f, 0.f};
        sacc = __builtin_amdgcn_mfma_f32_16x16x32_bf16(Fones, Fh, sacc, 0, 0, 0);
        sacc = __builtin_amdgcn_mfma_f32_16x16x32_bf16(Fones, Fl, sacc, 0, 0, 0);
        if (g == 0) vbuf[jc] = sacc[0];

        // ---- C = G - s s^T / 25 ----
        float s_jc = vbuf[jc] * i25;
        float4 s4 = *(const float4*)(vbuf + q4);
        float a0 = fmaf(-s4.x, s_jc, gacc[0]);
        float a1 = fmaf(-s4.y, s_jc, gacc[1]);
        float a2 = fmaf(-s4.z, s_jc, gacc[2]);
        float a3 = fmaf(-s4.w, s_jc, gacc[3]);

        // ---- NSQ trace-normalized squarings via split-bf16 MFMA (exact pairing) ----
        for (int sq = 0; sq < NSQ; ++sq) {
            Arow[(q4 + 0) * 20 + jc] = a0;
            Arow[(q4 + 1) * 20 + jc] = a1;
            Arow[(q4 + 2) * 20 + jc] = a2;
            Arow[(q4 + 3) * 20 + jc] = a3;
            *(float4*)(Acol + jc * 20 + q4) = make_float4(a0, a1, a2, a3);
            float t = 0.f;
            if (jc == q4 + 0) t += a0;
            if (jc == q4 + 1) t += a1;
            if (jc == q4 + 2) t += a2;
            if (jc == q4 + 3) t += a3;
#pragma unroll
            for (int off = 32; off >= 1; off >>= 1) t += __shfl_xor(t, off, 64);
            float itr = (t > 0.f) ? (1.0f / t) : 1.0f;

            // A-frags: row l15 of A, cols c8..c8+7 -> hi and lo
            float4 ar0 = *(const float4*)(Arow + l15 * 20 + c8);
            float4 ar1 = *(const float4*)(Arow + l15 * 20 + c8 + 4);
            float av[8] = {ar0.x, ar0.y, ar0.z, ar0.w, ar1.x, ar1.y, ar1.z, ar1.w};
            bf16x8 AFh, AFl;
#pragma unroll
            for (int i = 0; i < 8; ++i) {
                unsigned short hh = f2bf(av[i]);
                float hf = __uint_as_float(((unsigned)hh) << 16);
                unsigned short ll = f2bf(av[i] - hf);
                AFh[i] = (short)hh;
                AFl[i] = (short)ll;
            }
            // B-frag: rows c8..c8+7 of A, col l15; hi for g<2, lo for g>=2
            float4 bc0 = *(const float4*)(Acol + l15 * 20 + c8);
            float4 bc1 = *(const float4*)(Acol + l15 * 20 + c8 + 4);
            float bv[8] = {bc0.x, bc0.y, bc0.z, bc0.w, bc1.x, bc1.y, bc1.z, bc1.w};
            bf16x8 BF;
#pragma unroll
            for (int i = 0; i < 8; ++i) {
                unsigned short hh = f2bf(bv[i]);
                if (g < 2) BF[i] = (short)hh;
                else {
                    float hf = __uint_as_float(((unsigned)hh) << 16);
                    BF[i] = (short)f2bf(bv[i] - hf);
                }
            }
            f32x4 acc = {0.f, 0.f, 0.f, 0.f};
            acc = __builtin_amdgcn_mfma_f32_16x16x32_bf16(AFh, BF, acc, 0, 0, 0);
            acc = __builtin_amdgcn_mfma_f32_16x16x32_bf16(AFl, BF, acc, 0, 0, 0);
            float sc = itr * itr;
            a0 = acc[0] * sc; a1 = acc[1] * sc; a2 = acc[2] * sc; a3 = acc[3] * sc;
        }

        // ---- column norms + argmax (tie: lower j) ----
        float cn = a0 * a0;
        cn = fmaf(a1, a1, cn); cn = fmaf(a2, a2, cn); cn = fmaf(a3, a3, cn);
        cn += __shfl_xor(cn, 16, 64);
        cn += __shfl_xor(cn, 32, 64);
        int bj = jc;
#pragma unroll
        for (int off = 32; off >= 1; off >>= 1) {
            float on = __shfl_xor(cn, off, 64);
            int   oj = __shfl_xor(bj, off, 64);
            if (on > cn || (on == cn && oj < bj)) { cn = on; bj = oj; }
        }

        if (jc == bj) {
            vbuf[q4 + 0] = a0; vbuf[q4 + 1] = a1;
            vbuf[q4 + 2] = a2; vbuf[q4 + 3] = a3;
        }
        float vj = vbuf[jc];
        float w0 = a0 * vj, w1 = a1 * vj, w2 = a2 * vj, w3 = a3 * vj;
#pragma unroll
        for (int off = 1; off < 16; off <<= 1) {
            w0 += __shfl_xor(w0, off, 64);
            w1 += __shfl_xor(w1, off, 64);
            w2 += __shfl_xor(w2, off, 64);
            w3 += __shfl_xor(w3, off, 64);
        }
        if (jc == 0) {
            vbuf[q4 + 0] = w0; vbuf[q4 + 1] = w1;
            vbuf[q4 + 2] = w2; vbuf[q4 + 3] = w3;
        }
        vj = vbuf[jc];
        float x0 = a0 * vj, x1 = a1 * vj, x2 = a2 * vj, x3 = a3 * vj;
#pragma unroll
        for (int off = 1; off < 16; off <<= 1) {
            x0 += __shfl_xor(x0, off, 64);
            x1 += __shfl_xor(x1, off, 64);
            x2 += __shfl_xor(x2, off, 64);
            x3 += __shfl_xor(x3, off, 64);
        }
        float nv = x0 * x0;
        nv = fmaf(x1, x1, nv); nv = fmaf(x2, x2, nv); nv = fmaf(x3, x3, nv);
        nv += __shfl_xor(nv, 16, 64);
        nv += __shfl_xor(nv, 32, 64);
        float inv = rsqrtf(fmaxf(nv, 1e-30f));
        if (jc == 0) {
            ubuf[m * 16 + q4 + 0] = x0 * inv;
            ubuf[m * 16 + q4 + 1] = x1 * inv;
            ubuf[m * 16 + q4 + 2] = x2 * inv;
            ubuf[m * 16 + q4 + 3] = x3 * inv;
        }
    }
    float du = ubuf[jc] * ubuf[16 + jc];
#pragma unroll
    for (int off = 1; off < 16; off <<= 1) du += __shfl_xor(du, off, 64);
    if (lane == 0) tsa[qi] = 2.0f - 2.0f * du * du;
}

// ---------------- finalize ----------------
__global__ void finalize_kernel(const float* __restrict__ tsa,
                                const float* __restrict__ part,
                                float* __restrict__ out) {
    __shared__ float red[256];
    int tid = threadIdx.x;
    float s = 0.f;
    for (int i = tid; i < BN; i += 256) s += tsa[i];
    red[tid] = s;
    __syncthreads();
    for (int off = 128; off > 0; off >>= 1) {
        if (tid < off) red[tid] += red[tid + off];
        __syncthreads();
    }
    float tsaSum = red[0];
    __syncthreads();
    red[tid] = part[tid];
    __syncthreads();
    for (int off = 128; off > 0; off >>= 1) {
        if (tid < off) red[tid] += red[tid + off];
        __syncthreads();
    }
    if (tid == 0)
        out[0] = red[0] * (1.0f / (float)(BN * DD)) + 0.1f * (tsaSum * (1.0f / (float)BN));
}

extern "C" void kernel_launch(void* const* d_in, const int* in_sizes, int n_in,
                              void* d_out, int out_size, void* d_ws, size_t ws_size,
                              hipStream_t stream) {
    const float* outputs = (const float*)d_in[0];
    const float* targets = (const float*)d_in[1];
    const float* latent  = (const float*)d_in[2];
    const float* raw     = (const float*)d_in[3];

    char* base = (char*)d_ws;
    float*    tsa   = (float*)base;                                   // BN f32
    float*    part  = (float*)(base + BN * 4);                        // 256 f32
    float*    nrm   = (float*)(base + BN * 4 + 1024);                 // BN f32
    float*    bndp  = (float*)(base + 2 * BN * 4 + 1024);             // BN f32
    uint4*    rawhl = (uint4*)(base + 3 * BN * 4 + 1024);             // BN*64 B
    unsigned* gcnt2 = (unsigned*)(base + 3 * BN * 4 + 1024 + BN * 64);  // BN*2 u32
    u64*      glist = (u64*)(base + 3 * BN * 4 + 1024 + BN * 64 + BN * 8); // BN*2*CAPH u64

    prep_kernel<<<BN / 256, 256, 0, stream>>>(raw, rawhl, nrm);
    recon_kernel<<<256, 256, 0, stream>>>(outputs, targets, part);
    bounds_kernel<<<BN / QB, 256, 0, stream>>>(rawhl, nrm, bndp);
    knnb_kernel<<<2 * (BN / QB), 256, 0, stream>>>(rawhl, nrm, bndp, gcnt2, glist);
    sel_eigen_kernel<<<BN / 4, 256, 0, stream>>>(latent, raw, gcnt2, glist, tsa);
    finalize_kernel<<<1, 256, 0, stream>>>(tsa, part, (float*)d_out);
}

// Round 21
// 233.255 us; speedup vs baseline: 1.1504x; 1.1504x over previous
//
#include <hip/hip_runtime.h>

#define BN 16384
#define DD 16
#define KNN 25
#define QB 16
#define CAPH 128
#define NSQ 4

typedef unsigned long long u64;
typedef __attribute__((ext_vector_type(8))) short bf16x8;
typedef __attribute__((ext_vector_type(4))) float f32x4;

__device__ __forceinline__ unsigned wave_min_u32(unsigned v) {
#pragma unroll
    for (int off = 32; off >= 1; off >>= 1) {
        unsigned o = __shfl_xor(v, off, 64);
        if (o < v) v = o;
    }
    return v;
}

__device__ __forceinline__ unsigned short f2bf(float f) {
    unsigned u = __float_as_uint(f);
    unsigned r = (u + 0x7FFFu + ((u >> 16) & 1u)) >> 16;   // RNE
    return (unsigned short)r;
}

// ---------------- prep: norms + split-precision bf16 [hi(16)|lo(16)] ----------------
__global__ void prep_kernel(const float* __restrict__ raw, uint4* __restrict__ rawhl,
                            float* __restrict__ nrm) {
    int j = blockIdx.x * 256 + threadIdx.x;
    if (j >= BN) return;
    const float4* rv = (const float4*)raw + j * 4;
    float4 a = rv[0], b = rv[1], c = rv[2], d = rv[3];
    float x[16] = {a.x,a.y,a.z,a.w,b.x,b.y,b.z,b.w,c.x,c.y,c.z,c.w,d.x,d.y,d.z,d.w};
    float s = 0.f;
#pragma unroll
    for (int i = 0; i < 16; ++i) s = fmaf(x[i], x[i], s);
    nrm[j] = s;
    unsigned hp[8], lp[8];
#pragma unroll
    for (int i = 0; i < 8; ++i) {
        unsigned short h0 = f2bf(x[2*i]), h1 = f2bf(x[2*i+1]);
        float f0 = __uint_as_float(((unsigned)h0) << 16);
        float f1 = __uint_as_float(((unsigned)h1) << 16);
        unsigned short l0 = f2bf(x[2*i] - f0), l1 = f2bf(x[2*i+1] - f1);
        hp[i] = (unsigned)h0 | ((unsigned)h1 << 16);
        lp[i] = (unsigned)l0 | ((unsigned)l1 << 16);
    }
    uint4* dst = rawhl + j * 4;
    dst[0] = make_uint4(hp[0], hp[1], hp[2], hp[3]);
    dst[1] = make_uint4(hp[4], hp[5], hp[6], hp[7]);
    dst[2] = make_uint4(lp[0], lp[1], lp[2], lp[3]);
    dst[3] = make_uint4(lp[4], lp[5], lp[6], lp[7]);
}

// ---------------- recon partials ----------------
__global__ void recon_kernel(const float* __restrict__ o, const float* __restrict__ t,
                             float* __restrict__ part) {
    __shared__ float red[256];
    int tid = threadIdx.x;
    int idx = blockIdx.x * 256 + tid;
    float s = 0.f;
    for (int i = idx; i < BN * DD; i += 256 * 256) {
        float d = o[i] - t[i];
        s = fmaf(d, d, s);
    }
    red[tid] = s;
    __syncthreads();
    for (int off = 128; off > 0; off >>= 1) {
        if (tid < off) red[tid] += red[tid + off];
        __syncthreads();
    }
    if (tid == 0) part[blockIdx.x] = red[0];
}

// ------- bounds: one global bound per query from first-4096 sample -------
__global__ __launch_bounds__(256, 8) void bounds_kernel(const uint4* __restrict__ rawhl,
                                                        const float* __restrict__ nrm,
                                                        float* __restrict__ bndp) {
    const int tid  = threadIdx.x;
    const int lane = tid & 63;
    const int w    = tid >> 6;
    const int l15  = lane & 15;
    const int g    = lane >> 4;
    const int row0 = blockIdx.x * QB;

    __shared__ float minbuf[QB][64];   // 4 KB

    const bf16x8* rb = (const bf16x8*)rawhl;
    bf16x8 A1 = rb[(row0 + l15) * 4 + (g & 1)];
    bf16x8 A2 = rb[(row0 + l15) * 4 + 2 + (g & 1)];
    float4 vqn = *(const float4*)(nrm + row0 + g * 4);

    const float INFf = __builtin_inff();
    float mn0 = INFf, mn1 = INFf, mn2 = INFf, mn3 = INFf;
    for (int t = w; t < 256; t += 4) {
        int pt = t * 16 + l15;
        bf16x8 Bf = rb[pt * 4 + g];
        float pn = nrm[pt];
        f32x4 c = {0.f, 0.f, 0.f, 0.f};
        c = __builtin_amdgcn_mfma_f32_16x16x32_bf16(A1, Bf, c, 0, 0, 0);
        c = __builtin_amdgcn_mfma_f32_16x16x32_bf16(A2, Bf, c, 0, 0, 0);
        mn0 = fminf(mn0, fmaxf(fmaf(-2.f, c[0], vqn.x + pn), 0.f));
        mn1 = fminf(mn1, fmaxf(fmaf(-2.f, c[1], vqn.y + pn), 0.f));
        mn2 = fminf(mn2, fmaxf(fmaf(-2.f, c[2], vqn.z + pn), 0.f));
        mn3 = fminf(mn3, fmaxf(fmaf(-2.f, c[3], vqn.w + pn), 0.f));
    }
    minbuf[g * 4 + 0][w * 16 + l15] = mn0;
    minbuf[g * 4 + 1][w * 16 + l15] = mn1;
    minbuf[g * 4 + 2][w * 16 + l15] = mn2;
    minbuf[g * 4 + 3][w * 16 + l15] = mn3;
    __syncthreads();

    // 26 value-extractions: each retires >=1 distinct point's min => bound
    // >= true 26th-smallest over the sample >= global 26th-smallest.
    for (int rr = 0; rr < 4; ++rr) {
        int row = 4 * w + rr;
        float v = minbuf[row][lane];
        float bk = INFf;
        for (int it = 0; it < KNN + 1; ++it) {
            float m = v;
#pragma unroll
            for (int off = 32; off >= 1; off >>= 1)
                m = fminf(m, __shfl_xor(m, off, 64));
            bk = m;
            if (v == m) v = INFf;
        }
        // pre-shifted compare constant: (pn - 2c) <= bk - qn (+ rounding margin)
        if (lane == 0) bndp[row0 + row] = bk - nrm[row0 + row] + 1e-3f;
    }
}

// ------- knnb: 16 rows x half-point-range; u32-key LDS collect, coalesced flush -------
__global__ __launch_bounds__(256, 8) void knnb_kernel(const uint4* __restrict__ rawhl,
                                                      const float* __restrict__ nrm,
                                                      const float* __restrict__ bndp,
                                                      unsigned* __restrict__ gcnt2,
                                                      unsigned* __restrict__ glist) {
    const int tid  = threadIdx.x;
    const int lane = tid & 63;
    const int w    = tid >> 6;
    const int l15  = lane & 15;
    const int g    = lane >> 4;
    const int qg   = blockIdx.x >> 1;
    const int h    = blockIdx.x & 1;
    const int row0 = qg * QB;
    const int pbase = h * (BN / 2);

    __shared__ __align__(16) unsigned lists[QB][CAPH];   // 8 KB
    __shared__ int lcnt[QB];

    if (tid < QB) lcnt[tid] = 0;
    __syncthreads();

    const bf16x8* rb = (const bf16x8*)rawhl;
    bf16x8 A1 = rb[(row0 + l15) * 4 + (g & 1)];
    bf16x8 A2 = rb[(row0 + l15) * 4 + 2 + (g & 1)];
    float4 vqn = *(const float4*)(nrm + row0 + g * 4);
    float4 vbp = *(const float4*)(bndp + row0 + g * 4);

    // ---- single pass over this half: 2 VALU/dot test, rare collect ----
    // key = (f32bits(d2) & ~0x3FFF) | pt : 18-bit value primary, idx secondary
    for (int t = w; t < 512; t += 4) {
        int pt = pbase + t * 16 + l15;
        bf16x8 Bf = rb[pt * 4 + g];
        float pn = nrm[pt];
        f32x4 c = {0.f, 0.f, 0.f, 0.f};
        c = __builtin_amdgcn_mfma_f32_16x16x32_bf16(A1, Bf, c, 0, 0, 0);
        c = __builtin_amdgcn_mfma_f32_16x16x32_bf16(A2, Bf, c, 0, 0, 0);
#define COLL(r, QN, BB) { \
        float s = fmaf(-2.f, c[r], pn); \
        if (s <= BB) { \
            float d2 = fmaxf(s + QN, 0.f); \
            int q = g * 4 + r; \
            int pos = atomicAdd(&lcnt[q], 1); \
            if (pos < CAPH) \
                lists[q][pos] = (__float_as_uint(d2) & ~0x3FFFu) | (unsigned)pt; } }
        COLL(0, vqn.x, vbp.x) COLL(1, vqn.y, vbp.y)
        COLL(2, vqn.z, vbp.z) COLL(3, vqn.w, vbp.w)
#undef COLL
    }
    __syncthreads();

    // ---- flush: coalesced bulk writes, one count store per query-half ----
    for (int rr = 0; rr < 4; ++rr) {
        int qi = 4 * w + rr;
        int cnt = lcnt[qi]; if (cnt > CAPH) cnt = CAPH;
        unsigned* dst = glist + ((u64)(row0 + qi) * 2 + h) * CAPH;
        for (int e = lane; e < cnt; e += 64) dst[e] = lists[qi][e];
        if (lane == 0) gcnt2[(row0 + qi) * 2 + h] = (unsigned)cnt;
    }
}

// ------------- sel_eigen: 1 row per wave; u32 top-25 select, MFMA eigen solve -------------
__global__ __launch_bounds__(256, 8) void sel_eigen_kernel(const float* __restrict__ latent,
                                                           const float* __restrict__ raw,
                                                           const unsigned* __restrict__ gcnt2,
                                                           const unsigned* __restrict__ glist,
                                                           float* __restrict__ tsa) {
    const int lane = threadIdx.x & 63;
    const int w    = threadIdx.x >> 6;
    const int l15  = lane & 15;
    const int g    = lane >> 4;
    const int qi   = blockIdx.x * 4 + w;

    __shared__ __align__(16) float smem[4 * 720];   // 11.25 KB, wave-private slices
    float* ews  = smem + w * 720;
    float* pts  = ews;            // [0,640): 32 rows x stride 20 (overlaid later)
    float* Arow = ews;            // [0,320): overlay on pts
    float* Acol = ews + 320;      // [320,640): overlay on pts
    float* vbuf = ews + 640;      // 16
    float* ubuf = ews + 656;      // 32
    int*   nbrw = (int*)(ews + 688); // 25

    // ---- selection: merge 2 half-lists, register 26 extract-mins over u32 keys ----
    {
        int c0 = (int)gcnt2[qi * 2 + 0]; if (c0 > CAPH) c0 = CAPH;
        int c1 = (int)gcnt2[qi * 2 + 1]; if (c1 > CAPH) c1 = CAPH;
        const unsigned* L = glist + (u64)qi * 2 * CAPH;
        unsigned k0, k1, k2, k3;
#define GET(dst, i) { int ii = (i); \
        if (ii < c0) dst = L[ii]; \
        else { int jj = ii - c0; dst = (jj < c1) ? L[CAPH + jj] : 0xFFFFFFFFu; } }
        GET(k0, lane) GET(k1, lane + 64) GET(k2, lane + 128) GET(k3, lane + 192)
#undef GET
        for (int it = 0; it < KNN + 1; ++it) {
            unsigned best = k0;
            if (k1 < best) best = k1;
            if (k2 < best) best = k2;
            if (k3 < best) best = k3;
            best = wave_min_u32(best);
            if (k0 == best) k0 = 0xFFFFFFFFu;
            if (k1 == best) k1 = 0xFFFFFFFFu;
            if (k2 == best) k2 = 0xFFFFFFFFu;
            if (k3 == best) k3 = 0xFFFFFFFFu;
            if (lane == 0 && it > 0) nbrw[it - 1] = (int)(best & 0x3FFFu);
        }
    }

    const int q4 = g << 2;
    const int jc = l15;
    const int c8 = 8 * (g & 1);
    const float i25 = 1.0f / 25.0f;

    // ones A-fragment for column-sum MFMA: A[0][k]=1, rows 1..15 = 0
    bf16x8 Fones;
#pragma unroll
    for (int i = 0; i < 8; ++i) Fones[i] = (l15 == 0) ? (short)0x3F80 : (short)0;

    for (int m = 0; m < 2; ++m) {
        const float4* src4 = (const float4*)((m == 0) ? latent : raw);
        // write pts rows 0..24 (Arow/Acol of previous iteration are dead here)
        if (lane < KNN) {
            int nb = nbrw[lane];
            float4 r0 = src4[nb * 4 + 0], r1 = src4[nb * 4 + 1];
            float4 r2 = src4[nb * 4 + 2], r3 = src4[nb * 4 + 3];
            float4* dst = (float4*)(pts + lane * 20);
            dst[0] = r0; dst[1] = r1; dst[2] = r2; dst[3] = r3;
        }
        // zero pad rows 25..31 (re-done each m: overlay clobbers it)
        if (lane >= 25 && lane < 32) {
            float4 z = make_float4(0.f, 0.f, 0.f, 0.f);
            float4* dst = (float4*)(pts + lane * 20);
            dst[0] = z; dst[1] = z; dst[2] = z; dst[3] = z;
        }

        // ---- P fragments: F = P[8g+i][l15] (serves as A=P^T and B=P) ----
        bf16x8 Fh, Fl;
#pragma unroll
        for (int i = 0; i < 8; ++i) {
            float pv = pts[(8 * g + i) * 20 + l15];
            unsigned short hh = f2bf(pv);
            float hf = __uint_as_float(((unsigned)hh) << 16);
            unsigned short ll = f2bf(pv - hf);
            Fh[i] = (short)hh;
            Fl[i] = (short)ll;
        }
        // pts is DEAD from here on; Arow/Acol may overwrite its region.

        // ---- gram G = P^T P (4 MFMAs, full hi/lo cross terms) ----
        f32x4 gacc = {0.f, 0.f, 0.f, 0.f};
        gacc = __builtin_amdgcn_mfma_f32_16x16x32_bf16(Fh, Fh, gacc, 0, 0, 0);
        gacc = __builtin_amdgcn_mfma_f32_16x16x32_bf16(Fh, Fl, gacc, 0, 0, 0);
        gacc = __builtin_amdgcn_mfma_f32_16x16x32_bf16(Fl, Fh, gacc, 0, 0, 0);
        gacc = __builtin_amdgcn_mfma_f32_16x16x32_bf16(Fl, Fl, gacc, 0, 0, 0);

        // ---- column sums s = 1^T P via ones-row MFMA ----
        f32x4 sacc = {0.f, 0.f, 0.f, 0.f};
        sacc = __builtin_amdgcn_mfma_f32_16x16x32_bf16(Fones, Fh, sacc, 0, 0, 0);
        sacc = __builtin_amdgcn_mfma_f32_16x16x32_bf16(Fones, Fl, sacc, 0, 0, 0);
        if (g == 0) vbuf[jc] = sacc[0];

        // ---- C = G - s s^T / 25 ----
        float s_jc = vbuf[jc] * i25;
        float4 s4 = *(const float4*)(vbuf + q4);
        float a0 = fmaf(-s4.x, s_jc, gacc[0]);
        float a1 = fmaf(-s4.y, s_jc, gacc[1]);
        float a2 = fmaf(-s4.z, s_jc, gacc[2]);
        float a3 = fmaf(-s4.w, s_jc, gacc[3]);

        // ---- NSQ trace-normalized squarings via split-bf16 MFMA (exact pairing) ----
        for (int sq = 0; sq < NSQ; ++sq) {
            Arow[(q4 + 0) * 20 + jc] = a0;
            Arow[(q4 + 1) * 20 + jc] = a1;
            Arow[(q4 + 2) * 20 + jc] = a2;
            Arow[(q4 + 3) * 20 + jc] = a3;
            *(float4*)(Acol + jc * 20 + q4) = make_float4(a0, a1, a2, a3);
            float t = 0.f;
            if (jc == q4 + 0) t += a0;
            if (jc == q4 + 1) t += a1;
            if (jc == q4 + 2) t += a2;
            if (jc == q4 + 3) t += a3;
#pragma unroll
            for (int off = 32; off >= 1; off >>= 1) t += __shfl_xor(t, off, 64);
            float itr = (t > 0.f) ? (1.0f / t) : 1.0f;

            // A-frags: row l15 of A, cols c8..c8+7 -> hi and lo
            float4 ar0 = *(const float4*)(Arow + l15 * 20 + c8);
            float4 ar1 = *(const float4*)(Arow + l15 * 20 + c8 + 4);
            float av[8] = {ar0.x, ar0.y, ar0.z, ar0.w, ar1.x, ar1.y, ar1.z, ar1.w};
            bf16x8 AFh, AFl;
#pragma unroll
            for (int i = 0; i < 8; ++i) {
                unsigned short hh = f2bf(av[i]);
                float hf = __uint_as_float(((unsigned)hh) << 16);
                unsigned short ll = f2bf(av[i] - hf);
                AFh[i] = (short)hh;
                AFl[i] = (short)ll;
            }
            // B-frag: rows c8..c8+7 of A, col l15; hi for g<2, lo for g>=2
            float4 bc0 = *(const float4*)(Acol + l15 * 20 + c8);
            float4 bc1 = *(const float4*)(Acol + l15 * 20 + c8 + 4);
            float bv[8] = {bc0.x, bc0.y, bc0.z, bc0.w, bc1.x, bc1.y, bc1.z, bc1.w};
            bf16x8 BF;
#pragma unroll
            for (int i = 0; i < 8; ++i) {
                unsigned short hh = f2bf(bv[i]);
                if (g < 2) BF[i] = (short)hh;
                else {
                    float hf = __uint_as_float(((unsigned)hh) << 16);
                    BF[i] = (short)f2bf(bv[i] - hf);
                }
            }
            f32x4 acc = {0.f, 0.f, 0.f, 0.f};
            acc = __builtin_amdgcn_mfma_f32_16x16x32_bf16(AFh, BF, acc, 0, 0, 0);
            acc = __builtin_amdgcn_mfma_f32_16x16x32_bf16(AFl, BF, acc, 0, 0, 0);
            float sc = itr * itr;
            a0 = acc[0] * sc; a1 = acc[1] * sc; a2 = acc[2] * sc; a3 = acc[3] * sc;
        }

        // ---- column norms + argmax (tie: lower j) ----
        float cn = a0 * a0;
        cn = fmaf(a1, a1, cn); cn = fmaf(a2, a2, cn); cn = fmaf(a3, a3, cn);
        cn += __shfl_xor(cn, 16, 64);
        cn += __shfl_xor(cn, 32, 64);
        int bj = jc;
#pragma unroll
        for (int off = 32; off >= 1; off >>= 1) {
            float on = __shfl_xor(cn, off, 64);
            int   oj = __shfl_xor(bj, off, 64);
            if (on > cn || (on == cn && oj < bj)) { cn = on; bj = oj; }
        }

        if (jc == bj) {
            vbuf[q4 + 0] = a0; vbuf[q4 + 1] = a1;
            vbuf[q4 + 2] = a2; vbuf[q4 + 3] = a3;
        }
        float vj = vbuf[jc];
        float w0 = a0 * vj, w1 = a1 * vj, w2 = a2 * vj, w3 = a3 * vj;
#pragma unroll
        for (int off = 1; off < 16; off <<= 1) {
            w0 += __shfl_xor(w0, off, 64);
            w1 += __shfl_xor(w1, off, 64);
            w2 += __shfl_xor(w2, off, 64);
            w3 += __shfl_xor(w3, off, 64);
        }
        if (jc == 0) {
            vbuf[q4 + 0] = w0; vbuf[q4 + 1] = w1;
            vbuf[q4 + 2] = w2; vbuf[q4 + 3] = w3;
        }
        vj = vbuf[jc];
        float x0 = a0 * vj, x1 = a1 * vj, x2 = a2 * vj, x3 = a3 * vj;
#pragma unroll
        for (int off = 1; off < 16; off <<= 1) {
            x0 += __shfl_xor(x0, off, 64);
            x1 += __shfl_xor(x1, off, 64);
            x2 += __shfl_xor(x2, off, 64);
            x3 += __shfl_xor(x3, off, 64);
        }
        float nv = x0 * x0;
        nv = fmaf(x1, x1, nv); nv = fmaf(x2, x2, nv); nv = fmaf(x3, x3, nv);
        nv += __shfl_xor(nv, 16, 64);
        nv += __shfl_xor(nv, 32, 64);
        float inv = rsqrtf(fmaxf(nv, 1e-30f));
        if (jc == 0) {
            ubuf[m * 16 + q4 + 0] = x0 * inv;
            ubuf[m * 16 + q4 + 1] = x1 * inv;
            ubuf[m * 16 + q4 + 2] = x2 * inv;
            ubuf[m * 16 + q4 + 3] = x3 * inv;
        }
    }
    float du = ubuf[jc] * ubuf[16 + jc];
#pragma unroll
    for (int off = 1; off < 16; off <<= 1) du += __shfl_xor(du, off, 64);
    if (lane == 0) tsa[qi] = 2.0f - 2.0f * du * du;
}

// ---------------- finalize ----------------
__global__ void finalize_kernel(const float* __restrict__ tsa,
                                const float* __restrict__ part,
                                float* __restrict__ out) {
    __shared__ float red[256];
    int tid = threadIdx.x;
    float s = 0.f;
    for (int i = tid; i < BN; i += 256) s += tsa[i];
    red[tid] = s;
    __syncthreads();
    for (int off = 128; off > 0; off >>= 1) {
        if (tid < off) red[tid] += red[tid + off];
        __syncthreads();
    }
    float tsaSum = red[0];
    __syncthreads();
    red[tid] = part[tid];
    __syncthreads();
    for (int off = 128; off > 0; off >>= 1) {
        if (tid < off) red[tid] += red[tid + off];
        __syncthreads();
    }
    if (tid == 0)
        out[0] = red[0] * (1.0f / (float)(BN * DD)) + 0.1f * (tsaSum * (1.0f / (float)BN));
}

extern "C" void kernel_launch(void* const* d_in, const int* in_sizes, int n_in,
                              void* d_out, int out_size, void* d_ws, size_t ws_size,
                              hipStream_t stream) {
    const float* outputs = (const float*)d_in[0];
    const float* targets = (const float*)d_in[1];
    const float* latent  = (const float*)d_in[2];
    const float* raw     = (const float*)d_in[3];

    char* base = (char*)d_ws;
    float*    tsa   = (float*)base;                                   // BN f32
    float*    part  = (float*)(base + BN * 4);                        // 256 f32
    float*    nrm   = (float*)(base + BN * 4 + 1024);                 // BN f32
    float*    bndp  = (float*)(base + 2 * BN * 4 + 1024);             // BN f32
    uint4*    rawhl = (uint4*)(base + 3 * BN * 4 + 1024);             // BN*64 B
    unsigned* gcnt2 = (unsigned*)(base + 3 * BN * 4 + 1024 + BN * 64);  // BN*2 u32
    unsigned* glist = (unsigned*)(base + 3 * BN * 4 + 1024 + BN * 64 + BN * 8); // BN*2*CAPH u32

    prep_kernel<<<BN / 256, 256, 0, stream>>>(raw, rawhl, nrm);
    recon_kernel<<<256, 256, 0, stream>>>(outputs, targets, part);
    bounds_kernel<<<BN / QB, 256, 0, stream>>>(rawhl, nrm, bndp);
    knnb_kernel<<<2 * (BN / QB), 256, 0, stream>>>(rawhl, nrm, bndp, gcnt2, glist);
    sel_eigen_kernel<<<BN / 4, 256, 0, stream>>>(latent, raw, gcnt2, glist, tsa);
    finalize_kernel<<<1, 256, 0, stream>>>(tsa, part, (float*)d_out);
}

// Round 23
// 227.548 us; speedup vs baseline: 1.1793x; 1.0251x over previous
//
#include <hip/hip_runtime.h>

#define BN 16384
#define DD 16
#define KNN 25
#define QB 16
#define CAPH 128
#define NSQ 3

typedef unsigned long long u64;
typedef __attribute__((ext_vector_type(8))) short bf16x8;
typedef __attribute__((ext_vector_type(4))) float f32x4;

__device__ __forceinline__ unsigned wave_min_u32(unsigned v) {
#pragma unroll
    for (int off = 32; off >= 1; off >>= 1) {
        unsigned o = __shfl_xor(v, off, 64);
        if (o < v) v = o;
    }
    return v;
}

__device__ __forceinline__ unsigned short f2bf(float f) {
    unsigned u = __float_as_uint(f);
    unsigned r = (u + 0x7FFFu + ((u >> 16) & 1u)) >> 16;   // RNE
    return (unsigned short)r;
}

// ---------------- prep: norms + split-precision bf16 [hi(16)|lo(16)] ----------------
__global__ void prep_kernel(const float* __restrict__ raw, uint4* __restrict__ rawhl,
                            float* __restrict__ nrm) {
    int j = blockIdx.x * 256 + threadIdx.x;
    if (j >= BN) return;
    const float4* rv = (const float4*)raw + j * 4;
    float4 a = rv[0], b = rv[1], c = rv[2], d = rv[3];
    float x[16] = {a.x,a.y,a.z,a.w,b.x,b.y,b.z,b.w,c.x,c.y,c.z,c.w,d.x,d.y,d.z,d.w};
    float s = 0.f;
#pragma unroll
    for (int i = 0; i < 16; ++i) s = fmaf(x[i], x[i], s);
    nrm[j] = s;
    unsigned hp[8], lp[8];
#pragma unroll
    for (int i = 0; i < 8; ++i) {
        unsigned short h0 = f2bf(x[2*i]), h1 = f2bf(x[2*i+1]);
        float f0 = __uint_as_float(((unsigned)h0) << 16);
        float f1 = __uint_as_float(((unsigned)h1) << 16);
        unsigned short l0 = f2bf(x[2*i] - f0), l1 = f2bf(x[2*i+1] - f1);
        hp[i] = (unsigned)h0 | ((unsigned)h1 << 16);
        lp[i] = (unsigned)l0 | ((unsigned)l1 << 16);
    }
    uint4* dst = rawhl + j * 4;
    dst[0] = make_uint4(hp[0], hp[1], hp[2], hp[3]);
    dst[1] = make_uint4(hp[4], hp[5], hp[6], hp[7]);
    dst[2] = make_uint4(lp[0], lp[1], lp[2], lp[3]);
    dst[3] = make_uint4(lp[4], lp[5], lp[6], lp[7]);
}

// ---------------- recon partials ----------------
__global__ void recon_kernel(const float* __restrict__ o, const float* __restrict__ t,
                             float* __restrict__ part) {
    __shared__ float red[256];
    int tid = threadIdx.x;
    int idx = blockIdx.x * 256 + tid;
    float s = 0.f;
    for (int i = idx; i < BN * DD; i += 256 * 256) {
        float d = o[i] - t[i];
        s = fmaf(d, d, s);
    }
    red[tid] = s;
    __syncthreads();
    for (int off = 128; off > 0; off >>= 1) {
        if (tid < off) red[tid] += red[tid + off];
        __syncthreads();
    }
    if (tid == 0) part[blockIdx.x] = red[0];
}

// ------- bounds: one global bound per query from first-4096 sample -------
__global__ __launch_bounds__(256, 8) void bounds_kernel(const uint4* __restrict__ rawhl,
                                                        const float* __restrict__ nrm,
                                                        float* __restrict__ bndp) {
    const int tid  = threadIdx.x;
    const int lane = tid & 63;
    const int w    = tid >> 6;
    const int l15  = lane & 15;
    const int g    = lane >> 4;
    const int row0 = blockIdx.x * QB;

    __shared__ float minbuf[QB][64];   // 4 KB

    const bf16x8* rb = (const bf16x8*)rawhl;
    bf16x8 A1 = rb[(row0 + l15) * 4 + (g & 1)];
    bf16x8 A2 = rb[(row0 + l15) * 4 + 2 + (g & 1)];
    float4 vqn = *(const float4*)(nrm + row0 + g * 4);

    const float INFf = __builtin_inff();
    float mn0 = INFf, mn1 = INFf, mn2 = INFf, mn3 = INFf;
    for (int t = w; t < 256; t += 4) {
        int pt = t * 16 + l15;
        bf16x8 Bf = rb[pt * 4 + g];
        float pn = nrm[pt];
        f32x4 c = {0.f, 0.f, 0.f, 0.f};
        c = __builtin_amdgcn_mfma_f32_16x16x32_bf16(A1, Bf, c, 0, 0, 0);
        c = __builtin_amdgcn_mfma_f32_16x16x32_bf16(A2, Bf, c, 0, 0, 0);
        mn0 = fminf(mn0, fmaxf(fmaf(-2.f, c[0], vqn.x + pn), 0.f));
        mn1 = fminf(mn1, fmaxf(fmaf(-2.f, c[1], vqn.y + pn), 0.f));
        mn2 = fminf(mn2, fmaxf(fmaf(-2.f, c[2], vqn.z + pn), 0.f));
        mn3 = fminf(mn3, fmaxf(fmaf(-2.f, c[3], vqn.w + pn), 0.f));
    }
    minbuf[g * 4 + 0][w * 16 + l15] = mn0;
    minbuf[g * 4 + 1][w * 16 + l15] = mn1;
    minbuf[g * 4 + 2][w * 16 + l15] = mn2;
    minbuf[g * 4 + 3][w * 16 + l15] = mn3;
    __syncthreads();

    // 26 value-extractions: each retires >=1 distinct point's min => bound
    // >= true 26th-smallest over the sample >= global 26th-smallest.
    for (int rr = 0; rr < 4; ++rr) {
        int row = 4 * w + rr;
        float v = minbuf[row][lane];
        float bk = INFf;
        for (int it = 0; it < KNN + 1; ++it) {
            float m = v;
#pragma unroll
            for (int off = 32; off >= 1; off >>= 1)
                m = fminf(m, __shfl_xor(m, off, 64));
            bk = m;
            if (v == m) v = INFf;
        }
        // pre-shifted compare constant: (pn - 2c) <= bk - qn (+ rounding margin)
        if (lane == 0) bndp[row0 + row] = bk - nrm[row0 + row] + 1e-3f;
    }
}

// ------- knnb: 16 rows x half-point-range; u32-key LDS collect, coalesced flush -------
__global__ __launch_bounds__(256, 8) void knnb_kernel(const uint4* __restrict__ rawhl,
                                                      const float* __restrict__ nrm,
                                                      const float* __restrict__ bndp,
                                                      unsigned* __restrict__ gcnt2,
                                                      unsigned* __restrict__ glist) {
    const int tid  = threadIdx.x;
    const int lane = tid & 63;
    const int w    = tid >> 6;
    const int l15  = lane & 15;
    const int g    = lane >> 4;
    const int qg   = blockIdx.x >> 1;
    const int h    = blockIdx.x & 1;
    const int row0 = qg * QB;
    const int pbase = h * (BN / 2);

    __shared__ __align__(16) unsigned lists[QB][CAPH];   // 8 KB
    __shared__ int lcnt[QB];

    if (tid < QB) lcnt[tid] = 0;
    __syncthreads();

    const bf16x8* rb = (const bf16x8*)rawhl;
    bf16x8 A1 = rb[(row0 + l15) * 4 + (g & 1)];
    bf16x8 A2 = rb[(row0 + l15) * 4 + 2 + (g & 1)];
    float4 vqn = *(const float4*)(nrm + row0 + g * 4);
    float4 vbp = *(const float4*)(bndp + row0 + g * 4);

    // ---- single pass over this half: 2 VALU/dot test, rare collect ----
    // key = (f32bits(d2) & ~0x3FFF) | pt : 18-bit value primary, idx secondary
    for (int t = w; t < 512; t += 4) {
        int pt = pbase + t * 16 + l15;
        bf16x8 Bf = rb[pt * 4 + g];
        float pn = nrm[pt];
        f32x4 c = {0.f, 0.f, 0.f, 0.f};
        c = __builtin_amdgcn_mfma_f32_16x16x32_bf16(A1, Bf, c, 0, 0, 0);
        c = __builtin_amdgcn_mfma_f32_16x16x32_bf16(A2, Bf, c, 0, 0, 0);
#define COLL(r, QN, BB) { \
        float s = fmaf(-2.f, c[r], pn); \
        if (s <= BB) { \
            float d2 = fmaxf(s + QN, 0.f); \
            int q = g * 4 + r; \
            int pos = atomicAdd(&lcnt[q], 1); \
            if (pos < CAPH) \
                lists[q][pos] = (__float_as_uint(d2) & ~0x3FFFu) | (unsigned)pt; } }
        COLL(0, vqn.x, vbp.x) COLL(1, vqn.y, vbp.y)
        COLL(2, vqn.z, vbp.z) COLL(3, vqn.w, vbp.w)
#undef COLL
    }
    __syncthreads();

    // ---- flush: coalesced bulk writes, one count store per query-half ----
    for (int rr = 0; rr < 4; ++rr) {
        int qi = 4 * w + rr;
        int cnt = lcnt[qi]; if (cnt > CAPH) cnt = CAPH;
        unsigned* dst = glist + ((u64)(row0 + qi) * 2 + h) * CAPH;
        for (int e = lane; e < cnt; e += 64) dst[e] = lists[qi][e];
        if (lane == 0) gcnt2[(row0 + qi) * 2 + h] = (unsigned)cnt;
    }
}

// ------------- sel_eigen: 1 row per wave; u32 top-25 select, MFMA eigen solve -------------
__global__ __launch_bounds__(256, 8) void sel_eigen_kernel(const float* __restrict__ latent,
                                                           const float* __restrict__ raw,
                                                           const unsigned* __restrict__ gcnt2,
                                                           const unsigned* __restrict__ glist,
                                                           float* __restrict__ tsa) {
    const int lane = threadIdx.x & 63;
    const int w    = threadIdx.x >> 6;
    const int l15  = lane & 15;
    const int g    = lane >> 4;
    const int qi   = blockIdx.x * 4 + w;

    __shared__ __align__(16) float smem[4 * 720];   // 11.25 KB, wave-private slices
    float* ews  = smem + w * 720;
    float* pts  = ews;            // [0,640): 32 rows x stride 20 (overlaid later)
    float* Arow = ews;            // [0,320): overlay on pts
    float* Acol = ews + 320;      // [320,640): overlay on pts
    float* vbuf = ews + 640;      // 16
    float* ubuf = ews + 656;      // 32
    int*   nbrw = (int*)(ews + 688); // 25

    // ---- selection: merge 2 half-lists, register 26 extract-mins over u32 keys ----
    {
        int c0 = (int)gcnt2[qi * 2 + 0]; if (c0 > CAPH) c0 = CAPH;
        int c1 = (int)gcnt2[qi * 2 + 1]; if (c1 > CAPH) c1 = CAPH;
        const unsigned* L = glist + (u64)qi * 2 * CAPH;
        unsigned k0, k1, k2, k3;
#define GET(dst, i) { int ii = (i); \
        if (ii < c0) dst = L[ii]; \
        else { int jj = ii - c0; dst = (jj < c1) ? L[CAPH + jj] : 0xFFFFFFFFu; } }
        GET(k0, lane) GET(k1, lane + 64) GET(k2, lane + 128) GET(k3, lane + 192)
#undef GET
        for (int it = 0; it < KNN + 1; ++it) {
            unsigned best = k0;
            if (k1 < best) best = k1;
            if (k2 < best) best = k2;
            if (k3 < best) best = k3;
            best = wave_min_u32(best);
            if (k0 == best) k0 = 0xFFFFFFFFu;
            if (k1 == best) k1 = 0xFFFFFFFFu;
            if (k2 == best) k2 = 0xFFFFFFFFu;
            if (k3 == best) k3 = 0xFFFFFFFFu;
            if (lane == 0 && it > 0) nbrw[it - 1] = (int)(best & 0x3FFFu);
        }
    }

    const int q4 = g << 2;
    const int jc = l15;
    const int c8 = 8 * (g & 1);
    const float i25 = 1.0f / 25.0f;

    // ones A-fragment for column-sum MFMA: A[0][k]=1, rows 1..15 = 0
    bf16x8 Fones;
#pragma unroll
    for (int i = 0; i < 8; ++i) Fones[i] = (l15 == 0) ? (short)0x3F80 : (short)0;

    for (int m = 0; m < 2; ++m) {
        const float4* src4 = (const float4*)((m == 0) ? latent : raw);
        // write pts rows 0..24 (Arow/Acol of previous iteration are dead here)
        if (lane < KNN) {
            int nb = nbrw[lane];
            float4 r0 = src4[nb * 4 + 0], r1 = src4[nb * 4 + 1];
            float4 r2 = src4[nb * 4 + 2], r3 = src4[nb * 4 + 3];
            float4* dst = (float4*)(pts + lane * 20);
            dst[0] = r0; dst[1] = r1; dst[2] = r2; dst[3] = r3;
        }
        // zero pad rows 25..31 (re-done each m: overlay clobbers it)
        if (lane >= 25 && lane < 32) {
            float4 z = make_float4(0.f, 0.f, 0.f, 0.f);
            float4* dst = (float4*)(pts + lane * 20);
            dst[0] = z; dst[1] = z; dst[2] = z; dst[3] = z;
        }

        // ---- P fragments: F = P[8g+i][l15] (serves as A=P^T and B=P) ----
        bf16x8 Fh, Fl;
#pragma unroll
        for (int i = 0; i < 8; ++i) {
            float pv = pts[(8 * g + i) * 20 + l15];
            unsigned short hh = f2bf(pv);
            float hf = __uint_as_float(((unsigned)hh) << 16);
            unsigned short ll = f2bf(pv - hf);
            Fh[i] = (short)hh;
            Fl[i] = (short)ll;
        }
        // pts is DEAD from here on; Arow/Acol may overwrite its region.

        // ---- gram G = P^T P (4 MFMAs, full hi/lo cross terms) ----
        f32x4 gacc = {0.f, 0.f, 0.f, 0.f};
        gacc = __builtin_amdgcn_mfma_f32_16x16x32_bf16(Fh, Fh, gacc, 0, 0, 0);
        gacc = __builtin_amdgcn_mfma_f32_16x16x32_bf16(Fh, Fl, gacc, 0, 0, 0);
        gacc = __builtin_amdgcn_mfma_f32_16x16x32_bf16(Fl, Fh, gacc, 0, 0, 0);
        gacc = __builtin_amdgcn_mfma_f32_16x16x32_bf16(Fl, Fl, gacc, 0, 0, 0);

        // ---- column sums s = 1^T P via ones-row MFMA ----
        f32x4 sacc = {0.f, 0.f, 0.f, 0.f};
        sacc = __builtin_amdgcn_mfma_f32_16x16x32_bf16(Fones, Fh, sacc, 0, 0, 0);
        sacc = __builtin_amdgcn_mfma_f32_16x16x32_bf16(Fones, Fl, sacc, 0, 0, 0);
        if (g == 0) vbuf[jc] = sacc[0];

        // ---- C = G - s s^T / 25 ----
        float s_jc = vbuf[jc] * i25;
        float4 s4 = *(const float4*)(vbuf + q4);
        float a0 = fmaf(-s4.x, s_jc, gacc[0]);
        float a1 = fmaf(-s4.y, s_jc, gacc[1]);
        float a2 = fmaf(-s4.z, s_jc, gacc[2]);
        float a3 = fmaf(-s4.w, s_jc, gacc[3]);

        // ---- NSQ trace-normalized squarings via split-bf16 MFMA (exact pairing) ----
        for (int sq = 0; sq < NSQ; ++sq) {
            Arow[(q4 + 0) * 20 + jc] = a0;
            Arow[(q4 + 1) * 20 + jc] = a1;
            Arow[(q4 + 2) * 20 + jc] = a2;
            Arow[(q4 + 3) * 20 + jc] = a3;
            *(float4*)(Acol + jc * 20 + q4) = make_float4(a0, a1, a2, a3);
            float t = 0.f;
            if (jc == q4 + 0) t += a0;
            if (jc == q4 + 1) t += a1;
            if (jc == q4 + 2) t += a2;
            if (jc == q4 + 3) t += a3;
#pragma unroll
            for (int off = 32; off >= 1; off >>= 1) t += __shfl_xor(t, off, 64);
            float itr = (t > 0.f) ? (1.0f / t) : 1.0f;

            // A-frags: row l15 of A, cols c8..c8+7 -> hi and lo
            float4 ar0 = *(const float4*)(Arow + l15 * 20 + c8);
            float4 ar1 = *(const float4*)(Arow + l15 * 20 + c8 + 4);
            float av[8] = {ar0.x, ar0.y, ar0.z, ar0.w, ar1.x, ar1.y, ar1.z, ar1.w};
            bf16x8 AFh, AFl;
#pragma unroll
            for (int i = 0; i < 8; ++i) {
                unsigned short hh = f2bf(av[i]);
                float hf = __uint_as_float(((unsigned)hh) << 16);
                unsigned short ll = f2bf(av[i] - hf);
                AFh[i] = (short)hh;
                AFl[i] = (short)ll;
            }
            // B-frag: rows c8..c8+7 of A, col l15; hi for g<2, lo for g>=2
            float4 bc0 = *(const float4*)(Acol + l15 * 20 + c8);
            float4 bc1 = *(const float4*)(Acol + l15 * 20 + c8 + 4);
            float bv[8] = {bc0.x, bc0.y, bc0.z, bc0.w, bc1.x, bc1.y, bc1.z, bc1.w};
            bf16x8 BF;
#pragma unroll
            for (int i = 0; i < 8; ++i) {
                unsigned short hh = f2bf(bv[i]);
                if (g < 2) BF[i] = (short)hh;
                else {
                    float hf = __uint_as_float(((unsigned)hh) << 16);
                    BF[i] = (short)f2bf(bv[i] - hf);
                }
            }
            f32x4 acc = {0.f, 0.f, 0.f, 0.f};
            acc = __builtin_amdgcn_mfma_f32_16x16x32_bf16(AFh, BF, acc, 0, 0, 0);
            acc = __builtin_amdgcn_mfma_f32_16x16x32_bf16(AFl, BF, acc, 0, 0, 0);
            float sc = itr * itr;
            a0 = acc[0] * sc; a1 = acc[1] * sc; a2 = acc[2] * sc; a3 = acc[3] * sc;
        }

        // ---- column norms + argmax (tie: lower j) ----
        float cn = a0 * a0;
        cn = fmaf(a1, a1, cn); cn = fmaf(a2, a2, cn); cn = fmaf(a3, a3, cn);
        cn += __shfl_xor(cn, 16, 64);
        cn += __shfl_xor(cn, 32, 64);
        int bj = jc;
#pragma unroll
        for (int off = 32; off >= 1; off >>= 1) {
            float on = __shfl_xor(cn, off, 64);
            int   oj = __shfl_xor(bj, off, 64);
            if (on > cn || (on == cn && oj < bj)) { cn = on; bj = oj; }
        }

        if (jc == bj) {
            vbuf[q4 + 0] = a0; vbuf[q4 + 1] = a1;
            vbuf[q4 + 2] = a2; vbuf[q4 + 3] = a3;
        }
        float vj = vbuf[jc];
        float w0 = a0 * vj, w1 = a1 * vj, w2 = a2 * vj, w3 = a3 * vj;
#pragma unroll
        for (int off = 1; off < 16; off <<= 1) {
            w0 += __shfl_xor(w0, off, 64);
            w1 += __shfl_xor(w1, off, 64);
            w2 += __shfl_xor(w2, off, 64);
            w3 += __shfl_xor(w3, off, 64);
        }
        if (jc == 0) {
            vbuf[q4 + 0] = w0; vbuf[q4 + 1] = w1;
            vbuf[q4 + 2] = w2; vbuf[q4 + 3] = w3;
        }
        vj = vbuf[jc];
        float x0 = a0 * vj, x1 = a1 * vj, x2 = a2 * vj, x3 = a3 * vj;
#pragma unroll
        for (int off = 1; off < 16; off <<= 1) {
            x0 += __shfl_xor(x0, off, 64);
            x1 += __shfl_xor(x1, off, 64);
            x2 += __shfl_xor(x2, off, 64);
            x3 += __shfl_xor(x3, off, 64);
        }
        float nv = x0 * x0;
        nv = fmaf(x1, x1, nv); nv = fmaf(x2, x2, nv); nv = fmaf(x3, x3, nv);
        nv += __shfl_xor(nv, 16, 64);
        nv += __shfl_xor(nv, 32, 64);
        float inv = rsqrtf(fmaxf(nv, 1e-30f));
        if (jc == 0) {
            ubuf[m * 16 + q4 + 0] = x0 * inv;
            ubuf[m * 16 + q4 + 1] = x1 * inv;
            ubuf[m * 16 + q4 + 2] = x2 * inv;
            ubuf[m * 16 + q4 + 3] = x3 * inv;
        }
    }
    float du = ubuf[jc] * ubuf[16 + jc];
#pragma unroll
    for (int off = 1; off < 16; off <<= 1) du += __shfl_xor(du, off, 64);
    if (lane == 0) tsa[qi] = 2.0f - 2.0f * du * du;
}

// ---------------- finalize ----------------
__global__ void finalize_kernel(const float* __restrict__ tsa,
                                const float* __restrict__ part,
                                float* __restrict__ out) {
    __shared__ float red[256];
    int tid = threadIdx.x;
    float s = 0.f;
    for (int i = tid; i < BN; i += 256) s += tsa[i];
    red[tid] = s;
    __syncthreads();
    for (int off = 128; off > 0; off >>= 1) {
        if (tid < off) red[tid] += red[tid + off];
        __syncthreads();
    }
    float tsaSum = red[0];
    __syncthreads();
    red[tid] = part[tid];
    __syncthreads();
    for (int off = 128; off > 0; off >>= 1) {
        if (tid < off) red[tid] += red[tid + off];
        __syncthreads();
    }
    if (tid == 0)
        out[0] = red[0] * (1.0f / (float)(BN * DD)) + 0.1f * (tsaSum * (1.0f / (float)BN));
}

extern "C" void kernel_launch(void* const* d_in, const int* in_sizes, int n_in,
                              void* d_out, int out_size, void* d_ws, size_t ws_size,
                              hipStream_t stream) {
    const float* outputs = (const float*)d_in[0];
    const float* targets = (const float*)d_in[1];
    const float* latent  = (const float*)d_in[2];
    const float* raw     = (const float*)d_in[3];

    char* base = (char*)d_ws;
    float*    tsa   = (float*)base;                                   // BN f32
    float*    part  = (float*)(base + BN * 4);                        // 256 f32
    float*    nrm   = (float*)(base + BN * 4 + 1024);                 // BN f32
    float*    bndp  = (float*)(base + 2 * BN * 4 + 1024);             // BN f32
    uint4*    rawhl = (uint4*)(base + 3 * BN * 4 + 1024);             // BN*64 B
    unsigned* gcnt2 = (unsigned*)(base + 3 * BN * 4 + 1024 + BN * 64);  // BN*2 u32
    unsigned* glist = (unsigned*)(base + 3 * BN * 4 + 1024 + BN * 64 + BN * 8); // BN*2*CAPH u32

    prep_kernel<<<BN / 256, 256, 0, stream>>>(raw, rawhl, nrm);
    recon_kernel<<<256, 256, 0, stream>>>(outputs, targets, part);
    bounds_kernel<<<BN / QB, 256, 0, stream>>>(rawhl, nrm, bndp);
    knnb_kernel<<<2 * (BN / QB), 256, 0, stream>>>(rawhl, nrm, bndp, gcnt2, glist);
    sel_eigen_kernel<<<BN / 4, 256, 0, stream>>>(latent, raw, gcnt2, glist, tsa);
    finalize_kernel<<<1, 256, 0, stream>>>(tsa, part, (float*)d_out);
}

// Round 24
// 227.039 us; speedup vs baseline: 1.1819x; 1.0022x over previous
//
#include <hip/hip_runtime.h>

#define BN 16384
#define DD 16
#define KNN 25
#define QB 16
#define CAPH 128
#define NSQ 3

typedef unsigned long long u64;
typedef __attribute__((ext_vector_type(8))) short bf16x8;
typedef __attribute__((ext_vector_type(4))) float f32x4;

__device__ __forceinline__ unsigned wave_min_u32(unsigned v) {
#pragma unroll
    for (int off = 32; off >= 1; off >>= 1) {
        unsigned o = __shfl_xor(v, off, 64);
        if (o < v) v = o;
    }
    return v;
}

__device__ __forceinline__ unsigned short f2bf(float f) {
    unsigned u = __float_as_uint(f);
    unsigned r = (u + 0x7FFFu + ((u >> 16) & 1u)) >> 16;   // RNE
    return (unsigned short)r;
}

// ---------------- prep: norms + split-precision bf16 [hi(16)|lo(16)] ----------------
__global__ void prep_kernel(const float* __restrict__ raw, uint4* __restrict__ rawhl,
                            float* __restrict__ nrm) {
    int j = blockIdx.x * 256 + threadIdx.x;
    if (j >= BN) return;
    const float4* rv = (const float4*)raw + j * 4;
    float4 a = rv[0], b = rv[1], c = rv[2], d = rv[3];
    float x[16] = {a.x,a.y,a.z,a.w,b.x,b.y,b.z,b.w,c.x,c.y,c.z,c.w,d.x,d.y,d.z,d.w};
    float s = 0.f;
#pragma unroll
    for (int i = 0; i < 16; ++i) s = fmaf(x[i], x[i], s);
    nrm[j] = s;
    unsigned hp[8], lp[8];
#pragma unroll
    for (int i = 0; i < 8; ++i) {
        unsigned short h0 = f2bf(x[2*i]), h1 = f2bf(x[2*i+1]);
        float f0 = __uint_as_float(((unsigned)h0) << 16);
        float f1 = __uint_as_float(((unsigned)h1) << 16);
        unsigned short l0 = f2bf(x[2*i] - f0), l1 = f2bf(x[2*i+1] - f1);
        hp[i] = (unsigned)h0 | ((unsigned)h1 << 16);
        lp[i] = (unsigned)l0 | ((unsigned)l1 << 16);
    }
    uint4* dst = rawhl + j * 4;
    dst[0] = make_uint4(hp[0], hp[1], hp[2], hp[3]);
    dst[1] = make_uint4(hp[4], hp[5], hp[6], hp[7]);
    dst[2] = make_uint4(lp[0], lp[1], lp[2], lp[3]);
    dst[3] = make_uint4(lp[4], lp[5], lp[6], lp[7]);
}

// ---------------- recon partials ----------------
__global__ void recon_kernel(const float* __restrict__ o, const float* __restrict__ t,
                             float* __restrict__ part) {
    __shared__ float red[256];
    int tid = threadIdx.x;
    int idx = blockIdx.x * 256 + tid;
    float s = 0.f;
    for (int i = idx; i < BN * DD; i += 256 * 256) {
        float d = o[i] - t[i];
        s = fmaf(d, d, s);
    }
    red[tid] = s;
    __syncthreads();
    for (int off = 128; off > 0; off >>= 1) {
        if (tid < off) red[tid] += red[tid + off];
        __syncthreads();
    }
    if (tid == 0) part[blockIdx.x] = red[0];
}

// ------- bounds: one global bound per query from first-4096 sample -------
__global__ __launch_bounds__(256, 8) void bounds_kernel(const uint4* __restrict__ rawhl,
                                                        const float* __restrict__ nrm,
                                                        float* __restrict__ bndp) {
    const int tid  = threadIdx.x;
    const int lane = tid & 63;
    const int w    = tid >> 6;
    const int l15  = lane & 15;
    const int g    = lane >> 4;
    const int row0 = blockIdx.x * QB;

    __shared__ float minbuf[QB][64];   // 4 KB

    const bf16x8* rb = (const bf16x8*)rawhl;
    bf16x8 A1 = rb[(row0 + l15) * 4 + (g & 1)];
    bf16x8 A2 = rb[(row0 + l15) * 4 + 2 + (g & 1)];
    float4 vqn = *(const float4*)(nrm + row0 + g * 4);

    const float INFf = __builtin_inff();
    float mn0 = INFf, mn1 = INFf, mn2 = INFf, mn3 = INFf;
    for (int t = w; t < 256; t += 4) {
        int pt = t * 16 + l15;
        bf16x8 Bf = rb[pt * 4 + g];
        float pn = nrm[pt];
        f32x4 c = {0.f, 0.f, 0.f, 0.f};
        c = __builtin_amdgcn_mfma_f32_16x16x32_bf16(A1, Bf, c, 0, 0, 0);
        c = __builtin_amdgcn_mfma_f32_16x16x32_bf16(A2, Bf, c, 0, 0, 0);
        mn0 = fminf(mn0, fmaxf(fmaf(-2.f, c[0], vqn.x + pn), 0.f));
        mn1 = fminf(mn1, fmaxf(fmaf(-2.f, c[1], vqn.y + pn), 0.f));
        mn2 = fminf(mn2, fmaxf(fmaf(-2.f, c[2], vqn.z + pn), 0.f));
        mn3 = fminf(mn3, fmaxf(fmaf(-2.f, c[3], vqn.w + pn), 0.f));
    }
    minbuf[g * 4 + 0][w * 16 + l15] = mn0;
    minbuf[g * 4 + 1][w * 16 + l15] = mn1;
    minbuf[g * 4 + 2][w * 16 + l15] = mn2;
    minbuf[g * 4 + 3][w * 16 + l15] = mn3;
    __syncthreads();

    // 26 value-extractions: each retires >=1 distinct point's min => bound
    // >= true 26th-smallest over the sample >= global 26th-smallest.
    for (int rr = 0; rr < 4; ++rr) {
        int row = 4 * w + rr;
        float v = minbuf[row][lane];
        float bk = INFf;
        for (int it = 0; it < KNN + 1; ++it) {
            float m = v;
#pragma unroll
            for (int off = 32; off >= 1; off >>= 1)
                m = fminf(m, __shfl_xor(m, off, 64));
            bk = m;
            if (v == m) v = INFf;
        }
        // pre-shifted compare constant: (pn - 2c) <= bk - qn (+ rounding margin)
        if (lane == 0) bndp[row0 + row] = bk - nrm[row0 + row] + 1e-3f;
    }
}

// ------- knnb: 16 rows x half-point-range; u32-key LDS collect, coalesced flush -------
__global__ __launch_bounds__(256, 8) void knnb_kernel(const uint4* __restrict__ rawhl,
                                                      const float* __restrict__ nrm,
                                                      const float* __restrict__ bndp,
                                                      unsigned* __restrict__ gcnt2,
                                                      unsigned* __restrict__ glist) {
    const int tid  = threadIdx.x;
    const int lane = tid & 63;
    const int w    = tid >> 6;
    const int l15  = lane & 15;
    const int g    = lane >> 4;
    const int qg   = blockIdx.x >> 1;
    const int h    = blockIdx.x & 1;
    const int row0 = qg * QB;
    const int pbase = h * (BN / 2);

    __shared__ __align__(16) unsigned lists[QB][CAPH];   // 8 KB
    __shared__ int lcnt[QB];

    if (tid < QB) lcnt[tid] = 0;
    __syncthreads();

    const bf16x8* rb = (const bf16x8*)rawhl;
    bf16x8 A1 = rb[(row0 + l15) * 4 + (g & 1)];
    bf16x8 A2 = rb[(row0 + l15) * 4 + 2 + (g & 1)];
    float4 vqn = *(const float4*)(nrm + row0 + g * 4);
    float4 vbp = *(const float4*)(bndp + row0 + g * 4);

    // ---- single pass over this half: 2 VALU/dot test, rare collect ----
    // key = (f32bits(d2) & ~0x3FFF) | pt : 18-bit value primary, idx secondary
    for (int t = w; t < 512; t += 4) {
        int pt = pbase + t * 16 + l15;
        bf16x8 Bf = rb[pt * 4 + g];
        float pn = nrm[pt];
        f32x4 c = {0.f, 0.f, 0.f, 0.f};
        c = __builtin_amdgcn_mfma_f32_16x16x32_bf16(A1, Bf, c, 0, 0, 0);
        c = __builtin_amdgcn_mfma_f32_16x16x32_bf16(A2, Bf, c, 0, 0, 0);
#define COLL(r, QN, BB) { \
        float s = fmaf(-2.f, c[r], pn); \
        if (s <= BB) { \
            float d2 = fmaxf(s + QN, 0.f); \
            int q = g * 4 + r; \
            int pos = atomicAdd(&lcnt[q], 1); \
            if (pos < CAPH) \
                lists[q][pos] = (__float_as_uint(d2) & ~0x3FFFu) | (unsigned)pt; } }
        COLL(0, vqn.x, vbp.x) COLL(1, vqn.y, vbp.y)
        COLL(2, vqn.z, vbp.z) COLL(3, vqn.w, vbp.w)
#undef COLL
    }
    __syncthreads();

    // ---- flush: coalesced bulk writes, one count store per query-half ----
    for (int rr = 0; rr < 4; ++rr) {
        int qi = 4 * w + rr;
        int cnt = lcnt[qi]; if (cnt > CAPH) cnt = CAPH;
        unsigned* dst = glist + ((u64)(row0 + qi) * 2 + h) * CAPH;
        for (int e = lane; e < cnt; e += 64) dst[e] = lists[qi][e];
        if (lane == 0) gcnt2[(row0 + qi) * 2 + h] = (unsigned)cnt;
    }
}

// ---- sel_eigen: 1 row/wave; u32 select; DUAL-interleaved eigen with SEPARATE buffers ----
__global__ __launch_bounds__(256, 6) void sel_eigen_kernel(const float* __restrict__ latent,
                                                           const float* __restrict__ raw,
                                                           const unsigned* __restrict__ gcnt2,
                                                           const unsigned* __restrict__ glist,
                                                           float* __restrict__ tsa) {
    const int lane = threadIdx.x & 63;
    const int w    = threadIdx.x >> 6;
    const int l15  = lane & 15;
    const int g    = lane >> 4;
    const int qi   = blockIdx.x * 4 + w;

    __shared__ __align__(16) float smem[4 * 1376];   // 22 KB, wave-private slices
    float* ews   = smem + w * 1376;
    float* pts0  = ews;            // [0,640): latent pts; overlaid by Arow0/Acol0
    float* Arow0 = ews;            // [0,320)
    float* Acol0 = ews + 320;      // [320,640)
    float* pts1  = ews + 640;      // [640,1280): raw pts; overlaid by Arow1/Acol1
    float* Arow1 = ews + 640;      // [640,960)
    float* Acol1 = ews + 960;      // [960,1280)
    float* vbuf0 = ews + 1280;     // 16
    float* vbuf1 = ews + 1296;     // 16
    float* ubuf  = ews + 1312;     // 32
    int*   nbrw  = (int*)(ews + 1344); // 25

    // ---- selection: merge 2 half-lists, register 26 extract-mins over u32 keys ----
    {
        int c0 = (int)gcnt2[qi * 2 + 0]; if (c0 > CAPH) c0 = CAPH;
        int c1 = (int)gcnt2[qi * 2 + 1]; if (c1 > CAPH) c1 = CAPH;
        const unsigned* L = glist + (u64)qi * 2 * CAPH;
        unsigned k0, k1, k2, k3;
#define GET(dst, i) { int ii = (i); \
        if (ii < c0) dst = L[ii]; \
        else { int jj = ii - c0; dst = (jj < c1) ? L[CAPH + jj] : 0xFFFFFFFFu; } }
        GET(k0, lane) GET(k1, lane + 64) GET(k2, lane + 128) GET(k3, lane + 192)
#undef GET
        for (int it = 0; it < KNN + 1; ++it) {
            unsigned best = k0;
            if (k1 < best) best = k1;
            if (k2 < best) best = k2;
            if (k3 < best) best = k3;
            best = wave_min_u32(best);
            if (k0 == best) k0 = 0xFFFFFFFFu;
            if (k1 == best) k1 = 0xFFFFFFFFu;
            if (k2 == best) k2 = 0xFFFFFFFFu;
            if (k3 == best) k3 = 0xFFFFFFFFu;
            if (lane == 0 && it > 0) nbrw[it - 1] = (int)(best & 0x3FFFu);
        }
    }

    const int q4 = g << 2;
    const int jc = l15;
    const int c8 = 8 * (g & 1);
    const float i25 = 1.0f / 25.0f;

    // zero pad rows 25..31 of BOTH pts buffers
    if (lane >= 25 && lane < 32) {
        float4 z = make_float4(0.f, 0.f, 0.f, 0.f);
        float4* d0 = (float4*)(pts0 + lane * 20);
        d0[0] = z; d0[1] = z; d0[2] = z; d0[3] = z;
        float4* d1 = (float4*)(pts1 + lane * 20);
        d1[0] = z; d1[1] = z; d1[2] = z; d1[3] = z;
    }

    // ones A-fragment for column-sum MFMA: A[0][k]=1, rows 1..15 = 0
    bf16x8 Fones;
#pragma unroll
    for (int i = 0; i < 8; ++i) Fones[i] = (l15 == 0) ? (short)0x3F80 : (short)0;

    // load both point sets into their own buffers
    if (lane < KNN) {
        int nb = nbrw[lane];
        const float4* s0 = (const float4*)latent;
        float4 r0 = s0[nb * 4 + 0], r1 = s0[nb * 4 + 1];
        float4 r2 = s0[nb * 4 + 2], r3 = s0[nb * 4 + 3];
        float4* d0 = (float4*)(pts0 + lane * 20);
        d0[0] = r0; d0[1] = r1; d0[2] = r2; d0[3] = r3;
        const float4* s1 = (const float4*)raw;
        float4 t0 = s1[nb * 4 + 0], t1 = s1[nb * 4 + 1];
        float4 t2 = s1[nb * 4 + 2], t3 = s1[nb * 4 + 3];
        float4* d1 = (float4*)(pts1 + lane * 20);
        d1[0] = t0; d1[1] = t1; d1[2] = t2; d1[3] = t3;
    }

    // ---- P fragments from separate buffers ----
    bf16x8 F0h, F0l, F1h, F1l;
#pragma unroll
    for (int i = 0; i < 8; ++i) {
        float p0 = pts0[(8 * g + i) * 20 + l15];
        unsigned short h0 = f2bf(p0);
        float hf0 = __uint_as_float(((unsigned)h0) << 16);
        F0h[i] = (short)h0;
        F0l[i] = (short)f2bf(p0 - hf0);
        float p1 = pts1[(8 * g + i) * 20 + l15];
        unsigned short h1 = f2bf(p1);
        float hf1 = __uint_as_float(((unsigned)h1) << 16);
        F1h[i] = (short)h1;
        F1l[i] = (short)f2bf(p1 - hf1);
    }
    // pts0/pts1 DEAD from here; Arow/Acol overlays may overwrite.

    // ---- grams (interleaved) ----
    f32x4 gacc0 = {0.f, 0.f, 0.f, 0.f};
    f32x4 gacc1 = {0.f, 0.f, 0.f, 0.f};
    gacc0 = __builtin_amdgcn_mfma_f32_16x16x32_bf16(F0h, F0h, gacc0, 0, 0, 0);
    gacc1 = __builtin_amdgcn_mfma_f32_16x16x32_bf16(F1h, F1h, gacc1, 0, 0, 0);
    gacc0 = __builtin_amdgcn_mfma_f32_16x16x32_bf16(F0h, F0l, gacc0, 0, 0, 0);
    gacc1 = __builtin_amdgcn_mfma_f32_16x16x32_bf16(F1h, F1l, gacc1, 0, 0, 0);
    gacc0 = __builtin_amdgcn_mfma_f32_16x16x32_bf16(F0l, F0h, gacc0, 0, 0, 0);
    gacc1 = __builtin_amdgcn_mfma_f32_16x16x32_bf16(F1l, F1h, gacc1, 0, 0, 0);
    gacc0 = __builtin_amdgcn_mfma_f32_16x16x32_bf16(F0l, F0l, gacc0, 0, 0, 0);
    gacc1 = __builtin_amdgcn_mfma_f32_16x16x32_bf16(F1l, F1l, gacc1, 0, 0, 0);
    f32x4 sacc0 = {0.f, 0.f, 0.f, 0.f};
    f32x4 sacc1 = {0.f, 0.f, 0.f, 0.f};
    sacc0 = __builtin_amdgcn_mfma_f32_16x16x32_bf16(Fones, F0h, sacc0, 0, 0, 0);
    sacc1 = __builtin_amdgcn_mfma_f32_16x16x32_bf16(Fones, F1h, sacc1, 0, 0, 0);
    sacc0 = __builtin_amdgcn_mfma_f32_16x16x32_bf16(Fones, F0l, sacc0, 0, 0, 0);
    sacc1 = __builtin_amdgcn_mfma_f32_16x16x32_bf16(Fones, F1l, sacc1, 0, 0, 0);
    if (g == 0) { vbuf0[jc] = sacc0[0]; vbuf1[jc] = sacc1[0]; }

    // ---- C = G - s s^T / 25 (both) ----
    float sj0 = vbuf0[jc] * i25;
    float sj1 = vbuf1[jc] * i25;
    float4 s40 = *(const float4*)(vbuf0 + q4);
    float4 s41 = *(const float4*)(vbuf1 + q4);
    float a00 = fmaf(-s40.x, sj0, gacc0[0]);
    float a01 = fmaf(-s40.y, sj0, gacc0[1]);
    float a02 = fmaf(-s40.z, sj0, gacc0[2]);
    float a03 = fmaf(-s40.w, sj0, gacc0[3]);
    float a10 = fmaf(-s41.x, sj1, gacc1[0]);
    float a11 = fmaf(-s41.y, sj1, gacc1[1]);
    float a12 = fmaf(-s41.z, sj1, gacc1[2]);
    float a13 = fmaf(-s41.w, sj1, gacc1[3]);

    // ---- NSQ interleaved trace-normalized squarings ----
    for (int sq = 0; sq < NSQ; ++sq) {
        Arow0[(q4 + 0) * 20 + jc] = a00;
        Arow0[(q4 + 1) * 20 + jc] = a01;
        Arow0[(q4 + 2) * 20 + jc] = a02;
        Arow0[(q4 + 3) * 20 + jc] = a03;
        *(float4*)(Acol0 + jc * 20 + q4) = make_float4(a00, a01, a02, a03);
        Arow1[(q4 + 0) * 20 + jc] = a10;
        Arow1[(q4 + 1) * 20 + jc] = a11;
        Arow1[(q4 + 2) * 20 + jc] = a12;
        Arow1[(q4 + 3) * 20 + jc] = a13;
        *(float4*)(Acol1 + jc * 20 + q4) = make_float4(a10, a11, a12, a13);

        float t0 = 0.f, t1 = 0.f;
        if (jc == q4 + 0) { t0 += a00; t1 += a10; }
        if (jc == q4 + 1) { t0 += a01; t1 += a11; }
        if (jc == q4 + 2) { t0 += a02; t1 += a12; }
        if (jc == q4 + 3) { t0 += a03; t1 += a13; }
#pragma unroll
        for (int off = 32; off >= 1; off >>= 1) {
            t0 += __shfl_xor(t0, off, 64);
            t1 += __shfl_xor(t1, off, 64);
        }
        float itr0 = (t0 > 0.f) ? (1.0f / t0) : 1.0f;
        float itr1 = (t1 > 0.f) ? (1.0f / t1) : 1.0f;

#define SQFRAG(AR, AC, AFH, AFL, BF) { \
        float4 ar0 = *(const float4*)(AR + l15 * 20 + c8); \
        float4 ar1 = *(const float4*)(AR + l15 * 20 + c8 + 4); \
        float av[8] = {ar0.x, ar0.y, ar0.z, ar0.w, ar1.x, ar1.y, ar1.z, ar1.w}; \
        for (int i = 0; i < 8; ++i) { \
            unsigned short hh = f2bf(av[i]); \
            float hf = __uint_as_float(((unsigned)hh) << 16); \
            AFH[i] = (short)hh; AFL[i] = (short)f2bf(av[i] - hf); } \
        float4 bc0 = *(const float4*)(AC + l15 * 20 + c8); \
        float4 bc1 = *(const float4*)(AC + l15 * 20 + c8 + 4); \
        float bv[8] = {bc0.x, bc0.y, bc0.z, bc0.w, bc1.x, bc1.y, bc1.z, bc1.w}; \
        for (int i = 0; i < 8; ++i) { \
            unsigned short hh = f2bf(bv[i]); \
            if (g < 2) BF[i] = (short)hh; \
            else { \
                float hf = __uint_as_float(((unsigned)hh) << 16); \
                BF[i] = (short)f2bf(bv[i] - hf); } } }

        bf16x8 AF0h, AF0l, BF0, AF1h, AF1l, BF1;
        SQFRAG(Arow0, Acol0, AF0h, AF0l, BF0)
        SQFRAG(Arow1, Acol1, AF1h, AF1l, BF1)

        f32x4 acc0 = {0.f, 0.f, 0.f, 0.f};
        f32x4 acc1 = {0.f, 0.f, 0.f, 0.f};
        acc0 = __builtin_amdgcn_mfma_f32_16x16x32_bf16(AF0h, BF0, acc0, 0, 0, 0);
        acc1 = __builtin_amdgcn_mfma_f32_16x16x32_bf16(AF1h, BF1, acc1, 0, 0, 0);
        acc0 = __builtin_amdgcn_mfma_f32_16x16x32_bf16(AF0l, BF0, acc0, 0, 0, 0);
        acc1 = __builtin_amdgcn_mfma_f32_16x16x32_bf16(AF1l, BF1, acc1, 0, 0, 0);
        float sc0 = itr0 * itr0;
        float sc1 = itr1 * itr1;
        a00 = acc0[0] * sc0; a01 = acc0[1] * sc0; a02 = acc0[2] * sc0; a03 = acc0[3] * sc0;
        a10 = acc1[0] * sc1; a11 = acc1[1] * sc1; a12 = acc1[2] * sc1; a13 = acc1[3] * sc1;
    }

    // ---- column norms + argmax, both (tie: lower j) ----
    float cn0 = a00 * a00;
    cn0 = fmaf(a01, a01, cn0); cn0 = fmaf(a02, a02, cn0); cn0 = fmaf(a03, a03, cn0);
    float cn1 = a10 * a10;
    cn1 = fmaf(a11, a11, cn1); cn1 = fmaf(a12, a12, cn1); cn1 = fmaf(a13, a13, cn1);
    cn0 += __shfl_xor(cn0, 16, 64);
    cn1 += __shfl_xor(cn1, 16, 64);
    cn0 += __shfl_xor(cn0, 32, 64);
    cn1 += __shfl_xor(cn1, 32, 64);
    int bj0 = jc, bj1 = jc;
#pragma unroll
    for (int off = 32; off >= 1; off >>= 1) {
        float on0 = __shfl_xor(cn0, off, 64);
        int   oj0 = __shfl_xor(bj0, off, 64);
        float on1 = __shfl_xor(cn1, off, 64);
        int   oj1 = __shfl_xor(bj1, off, 64);
        if (on0 > cn0 || (on0 == cn0 && oj0 < bj0)) { cn0 = on0; bj0 = oj0; }
        if (on1 > cn1 || (on1 == cn1 && oj1 < bj1)) { cn1 = on1; bj1 = oj1; }
    }

    if (jc == bj0) {
        vbuf0[q4 + 0] = a00; vbuf0[q4 + 1] = a01;
        vbuf0[q4 + 2] = a02; vbuf0[q4 + 3] = a03;
    }
    if (jc == bj1) {
        vbuf1[q4 + 0] = a10; vbuf1[q4 + 1] = a11;
        vbuf1[q4 + 2] = a12; vbuf1[q4 + 3] = a13;
    }
    // matvec 1 (both)
    float vj0 = vbuf0[jc], vj1 = vbuf1[jc];
    float w00 = a00 * vj0, w01 = a01 * vj0, w02 = a02 * vj0, w03 = a03 * vj0;
    float w10 = a10 * vj1, w11 = a11 * vj1, w12 = a12 * vj1, w13 = a13 * vj1;
#pragma unroll
    for (int off = 1; off < 16; off <<= 1) {
        w00 += __shfl_xor(w00, off, 64); w01 += __shfl_xor(w01, off, 64);
        w02 += __shfl_xor(w02, off, 64); w03 += __shfl_xor(w03, off, 64);
        w10 += __shfl_xor(w10, off, 64); w11 += __shfl_xor(w11, off, 64);
        w12 += __shfl_xor(w12, off, 64); w13 += __shfl_xor(w13, off, 64);
    }
    if (jc == 0) {
        vbuf0[q4 + 0] = w00; vbuf0[q4 + 1] = w01;
        vbuf0[q4 + 2] = w02; vbuf0[q4 + 3] = w03;
        vbuf1[q4 + 0] = w10; vbuf1[q4 + 1] = w11;
        vbuf1[q4 + 2] = w12; vbuf1[q4 + 3] = w13;
    }
    // matvec 2 (both)
    vj0 = vbuf0[jc]; vj1 = vbuf1[jc];
    float x00 = a00 * vj0, x01 = a01 * vj0, x02 = a02 * vj0, x03 = a03 * vj0;
    float x10 = a10 * vj1, x11 = a11 * vj1, x12 = a12 * vj1, x13 = a13 * vj1;
#pragma unroll
    for (int off = 1; off < 16; off <<= 1) {
        x00 += __shfl_xor(x00, off, 64); x01 += __shfl_xor(x01, off, 64);
        x02 += __shfl_xor(x02, off, 64); x03 += __shfl_xor(x03, off, 64);
        x10 += __shfl_xor(x10, off, 64); x11 += __shfl_xor(x11, off, 64);
        x12 += __shfl_xor(x12, off, 64); x13 += __shfl_xor(x13, off, 64);
    }
    float nv0 = x00 * x00;
    nv0 = fmaf(x01, x01, nv0); nv0 = fmaf(x02, x02, nv0); nv0 = fmaf(x03, x03, nv0);
    float nv1 = x10 * x10;
    nv1 = fmaf(x11, x11, nv1); nv1 = fmaf(x12, x12, nv1); nv1 = fmaf(x13, x13, nv1);
    nv0 += __shfl_xor(nv0, 16, 64);
    nv1 += __shfl_xor(nv1, 16, 64);
    nv0 += __shfl_xor(nv0, 32, 64);
    nv1 += __shfl_xor(nv1, 32, 64);
    float inv0 = rsqrtf(fmaxf(nv0, 1e-30f));
    float inv1 = rsqrtf(fmaxf(nv1, 1e-30f));
    if (jc == 0) {
        ubuf[q4 + 0] = x00 * inv0; ubuf[q4 + 1] = x01 * inv0;
        ubuf[q4 + 2] = x02 * inv0; ubuf[q4 + 3] = x03 * inv0;
        ubuf[16 + q4 + 0] = x10 * inv1; ubuf[16 + q4 + 1] = x11 * inv1;
        ubuf[16 + q4 + 2] = x12 * inv1; ubuf[16 + q4 + 3] = x13 * inv1;
    }
    float du = ubuf[jc] * ubuf[16 + jc];
#pragma unroll
    for (int off = 1; off < 16; off <<= 1) du += __shfl_xor(du, off, 64);
    if (lane == 0) tsa[qi] = 2.0f - 2.0f * du * du;
}

// ---------------- finalize ----------------
__global__ void finalize_kernel(const float* __restrict__ tsa,
                                const float* __restrict__ part,
                                float* __restrict__ out) {
    __shared__ float red[256];
    int tid = threadIdx.x;
    float s = 0.f;
    for (int i = tid; i < BN; i += 256) s += tsa[i];
    red[tid] = s;
    __syncthreads();
    for (int off = 128; off > 0; off >>= 1) {
        if (tid < off) red[tid] += red[tid + off];
        __syncthreads();
    }
    float tsaSum = red[0];
    __syncthreads();
    red[tid] = part[tid];
    __syncthreads();
    for (int off = 128; off > 0; off >>= 1) {
        if (tid < off) red[tid] += red[tid + off];
        __syncthreads();
    }
    if (tid == 0)
        out[0] = red[0] * (1.0f / (float)(BN * DD)) + 0.1f * (tsaSum * (1.0f / (float)BN));
}

extern "C" void kernel_launch(void* const* d_in, const int* in_sizes, int n_in,
                              void* d_out, int out_size, void* d_ws, size_t ws_size,
                              hipStream_t stream) {
    const float* outputs = (const float*)d_in[0];
    const float* targets = (const float*)d_in[1];
    const float* latent  = (const float*)d_in[2];
    const float* raw     = (const float*)d_in[3];

    char* base = (char*)d_ws;
    float*    tsa   = (float*)base;                                   // BN f32
    float*    part  = (float*)(base + BN * 4);                        // 256 f32
    float*    nrm   = (float*)(base + BN * 4 + 1024);                 // BN f32
    float*    bndp  = (float*)(base + 2 * BN * 4 + 1024);             // BN f32
    uint4*    rawhl = (uint4*)(base + 3 * BN * 4 + 1024);             // BN*64 B
    unsigned* gcnt2 = (unsigned*)(base + 3 * BN * 4 + 1024 + BN * 64);  // BN*2 u32
    unsigned* glist = (unsigned*)(base + 3 * BN * 4 + 1024 + BN * 64 + BN * 8); // BN*2*CAPH u32

    prep_kernel<<<BN / 256, 256, 0, stream>>>(raw, rawhl, nrm);
    recon_kernel<<<256, 256, 0, stream>>>(outputs, targets, part);
    bounds_kernel<<<BN / QB, 256, 0, stream>>>(rawhl, nrm, bndp);
    knnb_kernel<<<2 * (BN / QB), 256, 0, stream>>>(rawhl, nrm, bndp, gcnt2, glist);
    sel_eigen_kernel<<<BN / 4, 256, 0, stream>>>(latent, raw, gcnt2, glist, tsa);
    finalize_kernel<<<1, 256, 0, stream>>>(tsa, part, (float*)d_out);
}

// Round 25
// 211.224 us; speedup vs baseline: 1.2704x; 1.0749x over previous
//
#include <hip/hip_runtime.h>

#define BN 16384
#define DD 16
#define KNN 25
#define QB 16
#define CAPH 128
#define NSQ 3
#define SMPT 192   // bounds sample tiles (x16 pts = 3072)

typedef unsigned long long u64;
typedef __attribute__((ext_vector_type(8))) short bf16x8;
typedef __attribute__((ext_vector_type(4))) float f32x4;

__device__ __forceinline__ unsigned wave_min_u32(unsigned v) {
#pragma unroll
    for (int off = 32; off >= 1; off >>= 1) {
        unsigned o = __shfl_xor(v, off, 64);
        if (o < v) v = o;
    }
    return v;
}

__device__ __forceinline__ unsigned short f2bf(float f) {
    unsigned u = __float_as_uint(f);
    unsigned r = (u + 0x7FFFu + ((u >> 16) & 1u)) >> 16;   // RNE
    return (unsigned short)r;
}

// ---------------- prep: norms + split-precision bf16 [hi(16)|lo(16)] ----------------
__global__ void prep_kernel(const float* __restrict__ raw, uint4* __restrict__ rawhl,
                            float* __restrict__ nrm) {
    int j = blockIdx.x * 256 + threadIdx.x;
    if (j >= BN) return;
    const float4* rv = (const float4*)raw + j * 4;
    float4 a = rv[0], b = rv[1], c = rv[2], d = rv[3];
    float x[16] = {a.x,a.y,a.z,a.w,b.x,b.y,b.z,b.w,c.x,c.y,c.z,c.w,d.x,d.y,d.z,d.w};
    float s = 0.f;
#pragma unroll
    for (int i = 0; i < 16; ++i) s = fmaf(x[i], x[i], s);
    nrm[j] = s;
    unsigned hp[8], lp[8];
#pragma unroll
    for (int i = 0; i < 8; ++i) {
        unsigned short h0 = f2bf(x[2*i]), h1 = f2bf(x[2*i+1]);
        float f0 = __uint_as_float(((unsigned)h0) << 16);
        float f1 = __uint_as_float(((unsigned)h1) << 16);
        unsigned short l0 = f2bf(x[2*i] - f0), l1 = f2bf(x[2*i+1] - f1);
        hp[i] = (unsigned)h0 | ((unsigned)h1 << 16);
        lp[i] = (unsigned)l0 | ((unsigned)l1 << 16);
    }
    uint4* dst = rawhl + j * 4;
    dst[0] = make_uint4(hp[0], hp[1], hp[2], hp[3]);
    dst[1] = make_uint4(hp[4], hp[5], hp[6], hp[7]);
    dst[2] = make_uint4(lp[0], lp[1], lp[2], lp[3]);
    dst[3] = make_uint4(lp[4], lp[5], lp[6], lp[7]);
}

// ---------------- recon partials ----------------
__global__ void recon_kernel(const float* __restrict__ o, const float* __restrict__ t,
                             float* __restrict__ part) {
    __shared__ float red[256];
    int tid = threadIdx.x;
    int idx = blockIdx.x * 256 + tid;
    float s = 0.f;
    for (int i = idx; i < BN * DD; i += 256 * 256) {
        float d = o[i] - t[i];
        s = fmaf(d, d, s);
    }
    red[tid] = s;
    __syncthreads();
    for (int off = 128; off > 0; off >>= 1) {
        if (tid < off) red[tid] += red[tid + off];
        __syncthreads();
    }
    if (tid == 0) part[blockIdx.x] = red[0];
}

// ------- bounds: one global bound per query from first-3072 sample -------
__global__ __launch_bounds__(256, 8) void bounds_kernel(const uint4* __restrict__ rawhl,
                                                        const float* __restrict__ nrm,
                                                        float* __restrict__ bndp) {
    const int tid  = threadIdx.x;
    const int lane = tid & 63;
    const int w    = tid >> 6;
    const int l15  = lane & 15;
    const int g    = lane >> 4;
    const int row0 = blockIdx.x * QB;

    __shared__ float minbuf[QB][64];   // 4 KB

    const bf16x8* rb = (const bf16x8*)rawhl;
    bf16x8 A1 = rb[(row0 + l15) * 4 + (g & 1)];
    bf16x8 A2 = rb[(row0 + l15) * 4 + 2 + (g & 1)];
    float4 vqn = *(const float4*)(nrm + row0 + g * 4);

    const float INFf = __builtin_inff();
    float mn0 = INFf, mn1 = INFf, mn2 = INFf, mn3 = INFf;
    for (int t = w; t < SMPT; t += 4) {
        int pt = t * 16 + l15;
        bf16x8 Bf = rb[pt * 4 + g];
        float pn = nrm[pt];
        f32x4 c = {0.f, 0.f, 0.f, 0.f};
        c = __builtin_amdgcn_mfma_f32_16x16x32_bf16(A1, Bf, c, 0, 0, 0);
        c = __builtin_amdgcn_mfma_f32_16x16x32_bf16(A2, Bf, c, 0, 0, 0);
        mn0 = fminf(mn0, fmaxf(fmaf(-2.f, c[0], vqn.x + pn), 0.f));
        mn1 = fminf(mn1, fmaxf(fmaf(-2.f, c[1], vqn.y + pn), 0.f));
        mn2 = fminf(mn2, fmaxf(fmaf(-2.f, c[2], vqn.z + pn), 0.f));
        mn3 = fminf(mn3, fmaxf(fmaf(-2.f, c[3], vqn.w + pn), 0.f));
    }
    minbuf[g * 4 + 0][w * 16 + l15] = mn0;
    minbuf[g * 4 + 1][w * 16 + l15] = mn1;
    minbuf[g * 4 + 2][w * 16 + l15] = mn2;
    minbuf[g * 4 + 3][w * 16 + l15] = mn3;
    __syncthreads();

    // 26 value-extractions: each retires >=1 distinct point's min => bound
    // >= true 26th-smallest over the sample >= global 26th-smallest.
    for (int rr = 0; rr < 4; ++rr) {
        int row = 4 * w + rr;
        float v = minbuf[row][lane];
        float bk = INFf;
        for (int it = 0; it < KNN + 1; ++it) {
            float m = v;
#pragma unroll
            for (int off = 32; off >= 1; off >>= 1)
                m = fminf(m, __shfl_xor(m, off, 64));
            bk = m;
            if (v == m) v = INFf;
        }
        // pre-shifted compare constant: (pn - 2c) <= bk - qn (+ rounding margin)
        if (lane == 0) bndp[row0 + row] = bk - nrm[row0 + row] + 1e-3f;
    }
}

// ------- knnb: 16 rows x half-point-range; u32-key LDS collect, coalesced flush -------
__global__ __launch_bounds__(256, 8) void knnb_kernel(const uint4* __restrict__ rawhl,
                                                      const float* __restrict__ nrm,
                                                      const float* __restrict__ bndp,
                                                      unsigned* __restrict__ gcnt2,
                                                      unsigned* __restrict__ glist) {
    const int tid  = threadIdx.x;
    const int lane = tid & 63;
    const int w    = tid >> 6;
    const int l15  = lane & 15;
    const int g    = lane >> 4;
    const int qg   = blockIdx.x >> 1;
    const int h    = blockIdx.x & 1;
    const int row0 = qg * QB;
    const int pbase = h * (BN / 2);

    __shared__ __align__(16) unsigned lists[QB][CAPH];   // 8 KB
    __shared__ int lcnt[QB];

    if (tid < QB) lcnt[tid] = 0;
    __syncthreads();

    const bf16x8* rb = (const bf16x8*)rawhl;
    bf16x8 A1 = rb[(row0 + l15) * 4 + (g & 1)];
    bf16x8 A2 = rb[(row0 + l15) * 4 + 2 + (g & 1)];
    float4 vqn = *(const float4*)(nrm + row0 + g * 4);
    float4 vbp = *(const float4*)(bndp + row0 + g * 4);

    // ---- single pass over this half: 2 VALU/dot test, rare collect ----
    // key = (f32bits(d2) & ~0x3FFF) | pt : 18-bit value primary, idx secondary
    for (int t = w; t < 512; t += 4) {
        int pt = pbase + t * 16 + l15;
        bf16x8 Bf = rb[pt * 4 + g];
        float pn = nrm[pt];
        f32x4 c = {0.f, 0.f, 0.f, 0.f};
        c = __builtin_amdgcn_mfma_f32_16x16x32_bf16(A1, Bf, c, 0, 0, 0);
        c = __builtin_amdgcn_mfma_f32_16x16x32_bf16(A2, Bf, c, 0, 0, 0);
#define COLL(r, QN, BB) { \
        float s = fmaf(-2.f, c[r], pn); \
        if (s <= BB) { \
            float d2 = fmaxf(s + QN, 0.f); \
            int q = g * 4 + r; \
            int pos = atomicAdd(&lcnt[q], 1); \
            if (pos < CAPH) \
                lists[q][pos] = (__float_as_uint(d2) & ~0x3FFFu) | (unsigned)pt; } }
        COLL(0, vqn.x, vbp.x) COLL(1, vqn.y, vbp.y)
        COLL(2, vqn.z, vbp.z) COLL(3, vqn.w, vbp.w)
#undef COLL
    }
    __syncthreads();

    // ---- flush: coalesced bulk writes, one count store per query-half ----
    for (int rr = 0; rr < 4; ++rr) {
        int qi = 4 * w + rr;
        int cnt = lcnt[qi]; if (cnt > CAPH) cnt = CAPH;
        unsigned* dst = glist + ((u64)(row0 + qi) * 2 + h) * CAPH;
        for (int e = lane; e < cnt; e += 64) dst[e] = lists[qi][e];
        if (lane == 0) gcnt2[(row0 + qi) * 2 + h] = (unsigned)cnt;
    }
}

// ---- sel_eigen: 1 row/wave; u32 select; DUAL-interleaved eigen with SEPARATE buffers ----
__global__ __launch_bounds__(256, 6) void sel_eigen_kernel(const float* __restrict__ latent,
                                                           const float* __restrict__ raw,
                                                           const unsigned* __restrict__ gcnt2,
                                                           const unsigned* __restrict__ glist,
                                                           float* __restrict__ tsa) {
    const int lane = threadIdx.x & 63;
    const int w    = threadIdx.x >> 6;
    const int l15  = lane & 15;
    const int g    = lane >> 4;
    const int qi   = blockIdx.x * 4 + w;

    __shared__ __align__(16) float smem[4 * 1376];   // 22 KB, wave-private slices
    float* ews   = smem + w * 1376;
    float* pts0  = ews;            // [0,640): latent pts; overlaid by Arow0/Acol0
    float* Arow0 = ews;            // [0,320)
    float* Acol0 = ews + 320;      // [320,640)
    float* pts1  = ews + 640;      // [640,1280): raw pts; overlaid by Arow1/Acol1
    float* Arow1 = ews + 640;      // [640,960)
    float* Acol1 = ews + 960;      // [960,1280)
    float* vbuf0 = ews + 1280;     // 16
    float* vbuf1 = ews + 1296;     // 16
    float* ubuf  = ews + 1312;     // 32
    int*   nbrw  = (int*)(ews + 1344); // 25

    // ---- selection: merge 2 half-lists, register 26 extract-mins over u32 keys ----
    {
        int c0 = (int)gcnt2[qi * 2 + 0]; if (c0 > CAPH) c0 = CAPH;
        int c1 = (int)gcnt2[qi * 2 + 1]; if (c1 > CAPH) c1 = CAPH;
        const unsigned* L = glist + (u64)qi * 2 * CAPH;
        unsigned k0, k1, k2, k3;
#define GET(dst, i) { int ii = (i); \
        if (ii < c0) dst = L[ii]; \
        else { int jj = ii - c0; dst = (jj < c1) ? L[CAPH + jj] : 0xFFFFFFFFu; } }
        GET(k0, lane) GET(k1, lane + 64) GET(k2, lane + 128) GET(k3, lane + 192)
#undef GET
        for (int it = 0; it < KNN + 1; ++it) {
            unsigned best = k0;
            if (k1 < best) best = k1;
            if (k2 < best) best = k2;
            if (k3 < best) best = k3;
            best = wave_min_u32(best);
            if (k0 == best) k0 = 0xFFFFFFFFu;
            if (k1 == best) k1 = 0xFFFFFFFFu;
            if (k2 == best) k2 = 0xFFFFFFFFu;
            if (k3 == best) k3 = 0xFFFFFFFFu;
            if (lane == 0 && it > 0) nbrw[it - 1] = (int)(best & 0x3FFFu);
        }
    }

    const int q4 = g << 2;
    const int jc = l15;
    const int c8 = 8 * (g & 1);
    const float i25 = 1.0f / 25.0f;

    // zero pad rows 25..31 of BOTH pts buffers
    if (lane >= 25 && lane < 32) {
        float4 z = make_float4(0.f, 0.f, 0.f, 0.f);
        float4* d0 = (float4*)(pts0 + lane * 20);
        d0[0] = z; d0[1] = z; d0[2] = z; d0[3] = z;
        float4* d1 = (float4*)(pts1 + lane * 20);
        d1[0] = z; d1[1] = z; d1[2] = z; d1[3] = z;
    }

    // ones A-fragment for column-sum MFMA: A[0][k]=1, rows 1..15 = 0
    bf16x8 Fones;
#pragma unroll
    for (int i = 0; i < 8; ++i) Fones[i] = (l15 == 0) ? (short)0x3F80 : (short)0;

    // load both point sets into their own buffers
    if (lane < KNN) {
        int nb = nbrw[lane];
        const float4* s0 = (const float4*)latent;
        float4 r0 = s0[nb * 4 + 0], r1 = s0[nb * 4 + 1];
        float4 r2 = s0[nb * 4 + 2], r3 = s0[nb * 4 + 3];
        float4* d0 = (float4*)(pts0 + lane * 20);
        d0[0] = r0; d0[1] = r1; d0[2] = r2; d0[3] = r3;
        const float4* s1 = (const float4*)raw;
        float4 t0 = s1[nb * 4 + 0], t1 = s1[nb * 4 + 1];
        float4 t2 = s1[nb * 4 + 2], t3 = s1[nb * 4 + 3];
        float4* d1 = (float4*)(pts1 + lane * 20);
        d1[0] = t0; d1[1] = t1; d1[2] = t2; d1[3] = t3;
    }

    // ---- P fragments from separate buffers ----
    bf16x8 F0h, F0l, F1h, F1l;
#pragma unroll
    for (int i = 0; i < 8; ++i) {
        float p0 = pts0[(8 * g + i) * 20 + l15];
        unsigned short h0 = f2bf(p0);
        float hf0 = __uint_as_float(((unsigned)h0) << 16);
        F0h[i] = (short)h0;
        F0l[i] = (short)f2bf(p0 - hf0);
        float p1 = pts1[(8 * g + i) * 20 + l15];
        unsigned short h1 = f2bf(p1);
        float hf1 = __uint_as_float(((unsigned)h1) << 16);
        F1h[i] = (short)h1;
        F1l[i] = (short)f2bf(p1 - hf1);
    }
    // pts0/pts1 DEAD from here; Arow/Acol overlays may overwrite.

    // ---- grams (interleaved) ----
    f32x4 gacc0 = {0.f, 0.f, 0.f, 0.f};
    f32x4 gacc1 = {0.f, 0.f, 0.f, 0.f};
    gacc0 = __builtin_amdgcn_mfma_f32_16x16x32_bf16(F0h, F0h, gacc0, 0, 0, 0);
    gacc1 = __builtin_amdgcn_mfma_f32_16x16x32_bf16(F1h, F1h, gacc1, 0, 0, 0);
    gacc0 = __builtin_amdgcn_mfma_f32_16x16x32_bf16(F0h, F0l, gacc0, 0, 0, 0);
    gacc1 = __builtin_amdgcn_mfma_f32_16x16x32_bf16(F1h, F1l, gacc1, 0, 0, 0);
    gacc0 = __builtin_amdgcn_mfma_f32_16x16x32_bf16(F0l, F0h, gacc0, 0, 0, 0);
    gacc1 = __builtin_amdgcn_mfma_f32_16x16x32_bf16(F1l, F1h, gacc1, 0, 0, 0);
    gacc0 = __builtin_amdgcn_mfma_f32_16x16x32_bf16(F0l, F0l, gacc0, 0, 0, 0);
    gacc1 = __builtin_amdgcn_mfma_f32_16x16x32_bf16(F1l, F1l, gacc1, 0, 0, 0);
    f32x4 sacc0 = {0.f, 0.f, 0.f, 0.f};
    f32x4 sacc1 = {0.f, 0.f, 0.f, 0.f};
    sacc0 = __builtin_amdgcn_mfma_f32_16x16x32_bf16(Fones, F0h, sacc0, 0, 0, 0);
    sacc1 = __builtin_amdgcn_mfma_f32_16x16x32_bf16(Fones, F1h, sacc1, 0, 0, 0);
    sacc0 = __builtin_amdgcn_mfma_f32_16x16x32_bf16(Fones, F0l, sacc0, 0, 0, 0);
    sacc1 = __builtin_amdgcn_mfma_f32_16x16x32_bf16(Fones, F1l, sacc1, 0, 0, 0);
    if (g == 0) { vbuf0[jc] = sacc0[0]; vbuf1[jc] = sacc1[0]; }

    // ---- C = G - s s^T / 25 (both) ----
    float sj0 = vbuf0[jc] * i25;
    float sj1 = vbuf1[jc] * i25;
    float4 s40 = *(const float4*)(vbuf0 + q4);
    float4 s41 = *(const float4*)(vbuf1 + q4);
    float a00 = fmaf(-s40.x, sj0, gacc0[0]);
    float a01 = fmaf(-s40.y, sj0, gacc0[1]);
    float a02 = fmaf(-s40.z, sj0, gacc0[2]);
    float a03 = fmaf(-s40.w, sj0, gacc0[3]);
    float a10 = fmaf(-s41.x, sj1, gacc1[0]);
    float a11 = fmaf(-s41.y, sj1, gacc1[1]);
    float a12 = fmaf(-s41.z, sj1, gacc1[2]);
    float a13 = fmaf(-s41.w, sj1, gacc1[3]);

    // ---- NSQ interleaved trace-normalized squarings ----
    for (int sq = 0; sq < NSQ; ++sq) {
        Arow0[(q4 + 0) * 20 + jc] = a00;
        Arow0[(q4 + 1) * 20 + jc] = a01;
        Arow0[(q4 + 2) * 20 + jc] = a02;
        Arow0[(q4 + 3) * 20 + jc] = a03;
        *(float4*)(Acol0 + jc * 20 + q4) = make_float4(a00, a01, a02, a03);
        Arow1[(q4 + 0) * 20 + jc] = a10;
        Arow1[(q4 + 1) * 20 + jc] = a11;
        Arow1[(q4 + 2) * 20 + jc] = a12;
        Arow1[(q4 + 3) * 20 + jc] = a13;
        *(float4*)(Acol1 + jc * 20 + q4) = make_float4(a10, a11, a12, a13);

        float t0 = 0.f, t1 = 0.f;
        if (jc == q4 + 0) { t0 += a00; t1 += a10; }
        if (jc == q4 + 1) { t0 += a01; t1 += a11; }
        if (jc == q4 + 2) { t0 += a02; t1 += a12; }
        if (jc == q4 + 3) { t0 += a03; t1 += a13; }
#pragma unroll
        for (int off = 32; off >= 1; off >>= 1) {
            t0 += __shfl_xor(t0, off, 64);
            t1 += __shfl_xor(t1, off, 64);
        }
        float itr0 = (t0 > 0.f) ? (1.0f / t0) : 1.0f;
        float itr1 = (t1 > 0.f) ? (1.0f / t1) : 1.0f;

#define SQFRAG(AR, AC, AFH, AFL, BF) { \
        float4 ar0 = *(const float4*)(AR + l15 * 20 + c8); \
        float4 ar1 = *(const float4*)(AR + l15 * 20 + c8 + 4); \
        float av[8] = {ar0.x, ar0.y, ar0.z, ar0.w, ar1.x, ar1.y, ar1.z, ar1.w}; \
        for (int i = 0; i < 8; ++i) { \
            unsigned short hh = f2bf(av[i]); \
            float hf = __uint_as_float(((unsigned)hh) << 16); \
            AFH[i] = (short)hh; AFL[i] = (short)f2bf(av[i] - hf); } \
        float4 bc0 = *(const float4*)(AC + l15 * 20 + c8); \
        float4 bc1 = *(const float4*)(AC + l15 * 20 + c8 + 4); \
        float bv[8] = {bc0.x, bc0.y, bc0.z, bc0.w, bc1.x, bc1.y, bc1.z, bc1.w}; \
        for (int i = 0; i < 8; ++i) { \
            unsigned short hh = f2bf(bv[i]); \
            if (g < 2) BF[i] = (short)hh; \
            else { \
                float hf = __uint_as_float(((unsigned)hh) << 16); \
                BF[i] = (short)f2bf(bv[i] - hf); } } }

        bf16x8 AF0h, AF0l, BF0, AF1h, AF1l, BF1;
        SQFRAG(Arow0, Acol0, AF0h, AF0l, BF0)
        SQFRAG(Arow1, Acol1, AF1h, AF1l, BF1)

        f32x4 acc0 = {0.f, 0.f, 0.f, 0.f};
        f32x4 acc1 = {0.f, 0.f, 0.f, 0.f};
        acc0 = __builtin_amdgcn_mfma_f32_16x16x32_bf16(AF0h, BF0, acc0, 0, 0, 0);
        acc1 = __builtin_amdgcn_mfma_f32_16x16x32_bf16(AF1h, BF1, acc1, 0, 0, 0);
        acc0 = __builtin_amdgcn_mfma_f32_16x16x32_bf16(AF0l, BF0, acc0, 0, 0, 0);
        acc1 = __builtin_amdgcn_mfma_f32_16x16x32_bf16(AF1l, BF1, acc1, 0, 0, 0);
        float sc0 = itr0 * itr0;
        float sc1 = itr1 * itr1;
        a00 = acc0[0] * sc0; a01 = acc0[1] * sc0; a02 = acc0[2] * sc0; a03 = acc0[3] * sc0;
        a10 = acc1[0] * sc1; a11 = acc1[1] * sc1; a12 = acc1[2] * sc1; a13 = acc1[3] * sc1;
    }

    // ---- column norms + argmax, both (tie: lower j) ----
    float cn0 = a00 * a00;
    cn0 = fmaf(a01, a01, cn0); cn0 = fmaf(a02, a02, cn0); cn0 = fmaf(a03, a03, cn0);
    float cn1 = a10 * a10;
    cn1 = fmaf(a11, a11, cn1); cn1 = fmaf(a12, a12, cn1); cn1 = fmaf(a13, a13, cn1);
    cn0 += __shfl_xor(cn0, 16, 64);
    cn1 += __shfl_xor(cn1, 16, 64);
    cn0 += __shfl_xor(cn0, 32, 64);
    cn1 += __shfl_xor(cn1, 32, 64);
    int bj0 = jc, bj1 = jc;
#pragma unroll
    for (int off = 32; off >= 1; off >>= 1) {
        float on0 = __shfl_xor(cn0, off, 64);
        int   oj0 = __shfl_xor(bj0, off, 64);
        float on1 = __shfl_xor(cn1, off, 64);
        int   oj1 = __shfl_xor(bj1, off, 64);
        if (on0 > cn0 || (on0 == cn0 && oj0 < bj0)) { cn0 = on0; bj0 = oj0; }
        if (on1 > cn1 || (on1 == cn1 && oj1 < bj1)) { cn1 = on1; bj1 = oj1; }
    }

    if (jc == bj0) {
        vbuf0[q4 + 0] = a00; vbuf0[q4 + 1] = a01;
        vbuf0[q4 + 2] = a02; vbuf0[q4 + 3] = a03;
    }
    if (jc == bj1) {
        vbuf1[q4 + 0] = a10; vbuf1[q4 + 1] = a11;
        vbuf1[q4 + 2] = a12; vbuf1[q4 + 3] = a13;
    }
    // matvec 1 (both)
    float vj0 = vbuf0[jc], vj1 = vbuf1[jc];
    float w00 = a00 * vj0, w01 = a01 * vj0, w02 = a02 * vj0, w03 = a03 * vj0;
    float w10 = a10 * vj1, w11 = a11 * vj1, w12 = a12 * vj1, w13 = a13 * vj1;
#pragma unroll
    for (int off = 1; off < 16; off <<= 1) {
        w00 += __shfl_xor(w00, off, 64); w01 += __shfl_xor(w01, off, 64);
        w02 += __shfl_xor(w02, off, 64); w03 += __shfl_xor(w03, off, 64);
        w10 += __shfl_xor(w10, off, 64); w11 += __shfl_xor(w11, off, 64);
        w12 += __shfl_xor(w12, off, 64); w13 += __shfl_xor(w13, off, 64);
    }
    if (jc == 0) {
        vbuf0[q4 + 0] = w00; vbuf0[q4 + 1] = w01;
        vbuf0[q4 + 2] = w02; vbuf0[q4 + 3] = w03;
        vbuf1[q4 + 0] = w10; vbuf1[q4 + 1] = w11;
        vbuf1[q4 + 2] = w12; vbuf1[q4 + 3] = w13;
    }
    // matvec 2 (both)
    vj0 = vbuf0[jc]; vj1 = vbuf1[jc];
    float x00 = a00 * vj0, x01 = a01 * vj0, x02 = a02 * vj0, x03 = a03 * vj0;
    float x10 = a10 * vj1, x11 = a11 * vj1, x12 = a12 * vj1, x13 = a13 * vj1;
#pragma unroll
    for (int off = 1; off < 16; off <<= 1) {
        x00 += __shfl_xor(x00, off, 64); x01 += __shfl_xor(x01, off, 64);
        x02 += __shfl_xor(x02, off, 64); x03 += __shfl_xor(x03, off, 64);
        x10 += __shfl_xor(x10, off, 64); x11 += __shfl_xor(x11, off, 64);
        x12 += __shfl_xor(x12, off, 64); x13 += __shfl_xor(x13, off, 64);
    }
    float nv0 = x00 * x00;
    nv0 = fmaf(x01, x01, nv0); nv0 = fmaf(x02, x02, nv0); nv0 = fmaf(x03, x03, nv0);
    float nv1 = x10 * x10;
    nv1 = fmaf(x11, x11, nv1); nv1 = fmaf(x12, x12, nv1); nv1 = fmaf(x13, x13, nv1);
    nv0 += __shfl_xor(nv0, 16, 64);
    nv1 += __shfl_xor(nv1, 16, 64);
    nv0 += __shfl_xor(nv0, 32, 64);
    nv1 += __shfl_xor(nv1, 32, 64);
    float inv0 = rsqrtf(fmaxf(nv0, 1e-30f));
    float inv1 = rsqrtf(fmaxf(nv1, 1e-30f));
    if (jc == 0) {
        ubuf[q4 + 0] = x00 * inv0; ubuf[q4 + 1] = x01 * inv0;
        ubuf[q4 + 2] = x02 * inv0; ubuf[q4 + 3] = x03 * inv0;
        ubuf[16 + q4 + 0] = x10 * inv1; ubuf[16 + q4 + 1] = x11 * inv1;
        ubuf[16 + q4 + 2] = x12 * inv1; ubuf[16 + q4 + 3] = x13 * inv1;
    }
    float du = ubuf[jc] * ubuf[16 + jc];
#pragma unroll
    for (int off = 1; off < 16; off <<= 1) du += __shfl_xor(du, off, 64);
    if (lane == 0) tsa[qi] = 2.0f - 2.0f * du * du;
}

// ---------------- finalize stage 1: 64-block partial sums of tsa ----------------
__global__ void finalize1_kernel(const float* __restrict__ tsa,
                                 float* __restrict__ partf) {
    __shared__ float red[256];
    int tid = threadIdx.x;
    red[tid] = tsa[blockIdx.x * 256 + tid];
    __syncthreads();
    for (int off = 128; off > 0; off >>= 1) {
        if (tid < off) red[tid] += red[tid + off];
        __syncthreads();
    }
    if (tid == 0) partf[blockIdx.x] = red[0];
}

// ---------------- finalize stage 2 ----------------
__global__ void finalize2_kernel(const float* __restrict__ partf,
                                 const float* __restrict__ part,
                                 float* __restrict__ out) {
    __shared__ float red[256];
    int tid = threadIdx.x;
    red[tid] = (tid < 64) ? partf[tid] : 0.f;
    __syncthreads();
    for (int off = 128; off > 0; off >>= 1) {
        if (tid < off) red[tid] += red[tid + off];
        __syncthreads();
    }
    float tsaSum = red[0];
    __syncthreads();
    red[tid] = part[tid];
    __syncthreads();
    for (int off = 128; off > 0; off >>= 1) {
        if (tid < off) red[tid] += red[tid + off];
        __syncthreads();
    }
    if (tid == 0)
        out[0] = red[0] * (1.0f / (float)(BN * DD)) + 0.1f * (tsaSum * (1.0f / (float)BN));
}

extern "C" void kernel_launch(void* const* d_in, const int* in_sizes, int n_in,
                              void* d_out, int out_size, void* d_ws, size_t ws_size,
                              hipStream_t stream) {
    const float* outputs = (const float*)d_in[0];
    const float* targets = (const float*)d_in[1];
    const float* latent  = (const float*)d_in[2];
    const float* raw     = (const float*)d_in[3];

    char* base = (char*)d_ws;
    float*    tsa   = (float*)base;                                   // BN f32
    float*    part  = (float*)(base + BN * 4);                        // 256 f32
    float*    nrm   = (float*)(base + BN * 4 + 1024);                 // BN f32
    float*    bndp  = (float*)(base + 2 * BN * 4 + 1024);             // BN f32
    uint4*    rawhl = (uint4*)(base + 3 * BN * 4 + 1024);             // BN*64 B
    unsigned* gcnt2 = (unsigned*)(base + 3 * BN * 4 + 1024 + BN * 64);  // BN*2 u32
    unsigned* glist = (unsigned*)(base + 3 * BN * 4 + 1024 + BN * 64 + BN * 8); // BN*2*CAPH u32
    float*    partf = (float*)(base + 3 * BN * 4 + 1024 + BN * 64 + BN * 8 + (u64)BN * 2 * CAPH * 4); // 64 f32

    prep_kernel<<<BN / 256, 256, 0, stream>>>(raw, rawhl, nrm);
    recon_kernel<<<256, 256, 0, stream>>>(outputs, targets, part);
    bounds_kernel<<<BN / QB, 256, 0, stream>>>(rawhl, nrm, bndp);
    knnb_kernel<<<2 * (BN / QB), 256, 0, stream>>>(rawhl, nrm, bndp, gcnt2, glist);
    sel_eigen_kernel<<<BN / 4, 256, 0, stream>>>(latent, raw, gcnt2, glist, tsa);
    finalize1_kernel<<<64, 256, 0, stream>>>(tsa, partf);
    finalize2_kernel<<<1, 256, 0, stream>>>(partf, part, (float*)d_out);
}